// Round 6
// baseline (737.916 us; speedup 1.0000x reference)
//
#include <hip/hip_runtime.h>
#include <math.h>

#define D 100
#define T 50
#define BB 512
#define NOUT 99999

__device__ __forceinline__ float sigf(float x) { return 1.f / (1.f + expf(-x)); }

// ===========================================================================
// Fused per-batch GGNN + attention kernel. One block per batch (512 blocks).
// LDS: hS (h, later h'), R1 (X1 -> a_in -> r*h -> seqW), R2 (X2 -> a_out -> u)
// Weight-GEMM phases register-tiled over t. Software pipelining ONLY in P3
// (adj prefetch) and P4 (k-pair ping-pong): deeper pipelining in all phases
// (r5) cost VGPR 128->228 and halved occupancy (2 blocks/CU -> 1) for a net
// LOSS. Register budget must stay < ~190 to keep 2 blocks/CU resident.
// ===========================================================================
__global__ __launch_bounds__(256) void ggnn_fused(
    const float* __restrict__ adj_in, const float* __restrict__ adj_out,
    const float* __restrict__ mask,   const int* __restrict__ item,
    const int* __restrict__ alias_,   const float* __restrict__ emb,
    const float* __restrict__ W_in,   const float* __restrict__ b_in,
    const float* __restrict__ W_out,  const float* __restrict__ b_out,
    const float* __restrict__ gate_k, const float* __restrict__ gate_b,
    const float* __restrict__ cand_k, const float* __restrict__ cand_b,
    const float* __restrict__ w1,     const float* __restrict__ w2,
    const float* __restrict__ v,      const float* __restrict__ nb,
    const float* __restrict__ Bm,     float* __restrict__ y1)
{
    __shared__ float hS[T*D];      // 20 KB
    __shared__ float R1[T*D];      // 20 KB
    __shared__ float R2[T*D];      // 20 KB
    __shared__ float maskS[T+2], vS[D], nbS[D], lastWS[D], coefS[T+2], maS[2*D];
    __shared__ int aliasS[T+2];
    __shared__ int rmidx;

    const int b = blockIdx.x, tid = threadIdx.x;
    const size_t bT = (size_t)b * T;

    // ---- P0: small stages ----
    if (tid < T) {
        aliasS[tid] = alias_[bT + tid];
        maskS[tid]  = mask[bT + tid];
    }
    if (tid >= 64 && tid < 64 + D) {
        int k = tid - 64;
        vS[k] = v[k]; nbS[k] = nb[k];
    }
    // ---- P1: h = emb[item] ----
    for (int idx = tid; idx < T*25; idx += 256) {
        int t = idx / 25, q = idx - t*25;
        int node = item[bT + t];
        *(float4*)&hS[t*D + q*4] = *(const float4*)&emb[(size_t)node*D + q*4];
    }
    __syncthreads();
    if (tid == 0) {
        float s = 0.f;
        for (int t = 0; t < T; ++t) s += maskS[t];
        rmidx = aliasS[(int)s - 1];
    }

    // role decode for the 250 active weight-GEMM threads
    const bool act250 = tid < 250;
    const int tg50  = tid / 50;      // 0..4 valid  (t-group of 10)
    const int rem50 = tid % 50;
    const int cg25  = tid / 25;      // 0..9 valid  (t-group of 5)
    const int jq25  = tid % 25;

    // ---- P2: X1 = h@W_in+b_in -> R1 ; X2 = h@W_out+b_out -> R2 ----
    // thread = (which, jq, tgroup of 10 t); weight quad loaded once per 10 t
    if (act250) {
        const int which = rem50 / 25, jq = rem50 % 25;
        const int t0 = tg50 * 10;
        const float* W  = which ? W_out : W_in;
        const float* bb = which ? b_out : b_in;
        float4 binit = *(const float4*)&bb[jq*4];
        float4 acc[10];
        #pragma unroll
        for (int tt = 0; tt < 10; ++tt) acc[tt] = binit;
        for (int k = 0; k < D; k += 2) {
            float4 wa = *(const float4*)&W[k*D + jq*4];
            float4 wb = *(const float4*)&W[(k+1)*D + jq*4];
            #pragma unroll
            for (int tt = 0; tt < 10; ++tt) {
                float2 a = *(const float2*)&hS[(t0+tt)*D + k];
                acc[tt].x += a.x*wa.x + a.y*wb.x;
                acc[tt].y += a.x*wa.y + a.y*wb.y;
                acc[tt].z += a.x*wa.z + a.y*wb.z;
                acc[tt].w += a.x*wa.w + a.y*wb.w;
            }
        }
        float* dst = which ? R2 : R1;
        #pragma unroll
        for (int tt = 0; tt < 10; ++tt)
            *(float4*)&dst[(t0+tt)*D + jq*4] = acc[tt];
    }
    __syncthreads();

    // ---- P3: a_in = adj_in@X1, a_out = adj_out@X2 (into regs) ----
    // prefetch next adj column while current column's FMAs run
    float4 eacc[10];
    if (act250) {
        const int which = rem50 / 25, jq = rem50 % 25;
        const int t0 = tg50 * 10;
        const float* adjp = which ? adj_out : adj_in;
        const float* Xs   = which ? R2 : R1;
        const float* apb  = &adjp[(bT + t0)*T];
        float ac[10], an[10];
        #pragma unroll
        for (int tt = 0; tt < 10; ++tt) {
            eacc[tt] = make_float4(0.f,0.f,0.f,0.f);
            ac[tt] = apb[tt*T];
        }
        #pragma unroll 1
        for (int s = 0; s < T-1; ++s) {
            #pragma unroll
            for (int tt = 0; tt < 10; ++tt) an[tt] = apb[tt*T + s + 1];
            float4 x = *(const float4*)&Xs[s*D + jq*4];
            #pragma unroll
            for (int tt = 0; tt < 10; ++tt) {
                eacc[tt].x += ac[tt]*x.x; eacc[tt].y += ac[tt]*x.y;
                eacc[tt].z += ac[tt]*x.z; eacc[tt].w += ac[tt]*x.w;
                ac[tt] = an[tt];
            }
        }
        float4 x = *(const float4*)&Xs[(T-1)*D + jq*4];
        #pragma unroll
        for (int tt = 0; tt < 10; ++tt) {
            eacc[tt].x += ac[tt]*x.x; eacc[tt].y += ac[tt]*x.y;
            eacc[tt].z += ac[tt]*x.z; eacc[tt].w += ac[tt]*x.w;
        }
    }
    __syncthreads();                 // all X reads done
    // ---- P3b: write a_in -> R1, a_out -> R2 ----
    if (act250) {
        const int which = rem50 / 25, jq = rem50 % 25;
        const int t0 = tg50 * 10;
        float* dst = which ? R2 : R1;
        #pragma unroll
        for (int tt = 0; tt < 10; ++tt)
            *(float4*)&dst[(t0+tt)*D + jq*4] = eacc[tt];
    }
    __syncthreads();

    // ---- P4: gates = sigmoid([a_in|a_out|h] @ gate_k + gate_b) into regs ----
    // k-pairs; ping-pong prefetch of 6 weight quads (3 segments x 2 k)
    float4 gacc[10];
    if (act250) {
        const int nq = rem50;
        const int t0 = tg50 * 10;
        float4 ginit = *(const float4*)&gate_b[nq*4];
        #pragma unroll
        for (int tt = 0; tt < 10; ++tt) gacc[tt] = ginit;

        float4 gq6[6], gp6[6];
#define P4_LOAD(dst, kp) { _Pragma("unroll") \
        for (int s = 0; s < 3; ++s) { \
            dst[s*2]   = *(const float4*)&gate_k[(size_t)((kp)+s*100)*200 + nq*4]; \
            dst[s*2+1] = *(const float4*)&gate_k[(size_t)((kp)+1+s*100)*200 + nq*4]; } }
#define P4_COMP(buf, kp) { _Pragma("unroll") \
        for (int tt = 0; tt < 10; ++tt) { \
            float2 a0 = *(const float2*)&R1[(t0+tt)*D + (kp)]; \
            float2 a1 = *(const float2*)&R2[(t0+tt)*D + (kp)]; \
            float2 a2 = *(const float2*)&hS[(t0+tt)*D + (kp)]; \
            gacc[tt].x += a0.x*buf[0].x + a0.y*buf[1].x + a1.x*buf[2].x + a1.y*buf[3].x + a2.x*buf[4].x + a2.y*buf[5].x; \
            gacc[tt].y += a0.x*buf[0].y + a0.y*buf[1].y + a1.x*buf[2].y + a1.y*buf[3].y + a2.x*buf[4].y + a2.y*buf[5].y; \
            gacc[tt].z += a0.x*buf[0].z + a0.y*buf[1].z + a1.x*buf[2].z + a1.y*buf[3].z + a2.x*buf[4].z + a2.y*buf[5].z; \
            gacc[tt].w += a0.x*buf[0].w + a0.y*buf[1].w + a1.x*buf[2].w + a1.y*buf[3].w + a2.x*buf[4].w + a2.y*buf[5].w; } }
        P4_LOAD(gq6, 0);
        #pragma unroll 1
        for (int k = 0; k < 96; k += 4) {
            P4_LOAD(gp6, k+2);  P4_COMP(gq6, k);
            P4_LOAD(gq6, k+4);  P4_COMP(gp6, k+2);
        }
        P4_LOAD(gp6, 98);
        P4_COMP(gq6, 96);
        P4_COMP(gp6, 98);

        #pragma unroll
        for (int tt = 0; tt < 10; ++tt) {
            gacc[tt].x = sigf(gacc[tt].x); gacc[tt].y = sigf(gacc[tt].y);
            gacc[tt].z = sigf(gacc[tt].z); gacc[tt].w = sigf(gacc[tt].w);
        }
    }

    // ---- P5a: cand partial (segments a_in, a_out) into regs ----
    // thread = (jq 0..24, tgroup of 5 t)   [NO prefetch: register peak here]
    float4 cacc[5];
    if (act250) {
        const int t0 = cg25 * 5;
        float4 cinit = *(const float4*)&cand_b[jq25*4];
        #pragma unroll
        for (int tt = 0; tt < 5; ++tt) cacc[tt] = cinit;
        for (int k = 0; k < D; k += 2) {
            float4 c0a = *(const float4*)&cand_k[(size_t)k*D + jq25*4];
            float4 c0b = *(const float4*)&cand_k[(size_t)(k+1)*D + jq25*4];
            float4 c1a = *(const float4*)&cand_k[(size_t)(k+100)*D + jq25*4];
            float4 c1b = *(const float4*)&cand_k[(size_t)(k+101)*D + jq25*4];
            #pragma unroll
            for (int tt = 0; tt < 5; ++tt) {
                float2 a0 = *(const float2*)&R1[(t0+tt)*D + k];
                float2 a1 = *(const float2*)&R2[(t0+tt)*D + k];
                cacc[tt].x += a0.x*c0a.x + a0.y*c0b.x + a1.x*c1a.x + a1.y*c1b.x;
                cacc[tt].y += a0.x*c0a.y + a0.y*c0b.y + a1.x*c1a.y + a1.y*c1b.y;
                cacc[tt].z += a0.x*c0a.z + a0.y*c0b.z + a1.x*c1a.z + a1.y*c1b.z;
                cacc[tt].w += a0.x*c0a.w + a0.y*c0b.w + a1.x*c1a.w + a1.y*c1b.w;
            }
        }
    }
    __syncthreads();                 // R1/R2 (a_in/a_out) reads done

    // ---- P5b: r-owners write r*h -> R1 ; u-owners write u -> R2 ----
    if (act250) {
        const int nq = rem50;
        const int t0 = tg50 * 10;
        if (nq < 25) {
            #pragma unroll
            for (int tt = 0; tt < 10; ++tt) {
                float4 hh = *(const float4*)&hS[(t0+tt)*D + nq*4];
                float4 g = gacc[tt];
                float4 o; o.x = g.x*hh.x; o.y = g.y*hh.y; o.z = g.z*hh.z; o.w = g.w*hh.w;
                *(float4*)&R1[(t0+tt)*D + nq*4] = o;
            }
        } else {
            #pragma unroll
            for (int tt = 0; tt < 10; ++tt)
                *(float4*)&R2[(t0+tt)*D + (nq-25)*4] = gacc[tt];
        }
    }
    __syncthreads();

    // ---- P5c: cand segment r*h + tanh; fused P7: h' = u*h+(1-u)*c -> hS ----
    if (act250) {
        const int t0 = cg25 * 5;
        for (int k = 0; k < D; k += 2) {
            float4 c2a = *(const float4*)&cand_k[(size_t)(k+200)*D + jq25*4];
            float4 c2b = *(const float4*)&cand_k[(size_t)(k+201)*D + jq25*4];
            #pragma unroll
            for (int tt = 0; tt < 5; ++tt) {
                float2 rh = *(const float2*)&R1[(t0+tt)*D + k];
                cacc[tt].x += rh.x*c2a.x + rh.y*c2b.x;
                cacc[tt].y += rh.x*c2a.y + rh.y*c2b.y;
                cacc[tt].z += rh.x*c2a.z + rh.y*c2b.z;
                cacc[tt].w += rh.x*c2a.w + rh.y*c2b.w;
            }
        }
        #pragma unroll
        for (int tt = 0; tt < 5; ++tt) {
            float4 c4;
            c4.x = tanhf(cacc[tt].x); c4.y = tanhf(cacc[tt].y);
            c4.z = tanhf(cacc[tt].z); c4.w = tanhf(cacc[tt].w);
            float4 u4 = *(const float4*)&R2[(t0+tt)*D + jq25*4];
            float4 hh = *(const float4*)&hS[(t0+tt)*D + jq25*4];
            float4 o;
            o.x = u4.x*hh.x + (1.f-u4.x)*c4.x;
            o.y = u4.y*hh.y + (1.f-u4.y)*c4.y;
            o.z = u4.z*hh.z + (1.f-u4.z)*c4.z;
            o.w = u4.w*hh.w + (1.f-u4.w)*c4.w;
            *(float4*)&hS[(t0+tt)*D + jq25*4] = o;
        }
    }
    __syncthreads();

    // ---- P8: seqW[t] = h'[alias[t]] @ w2 -> R1 ; lastW = h'[rmidx] @ w1 ----
    if (tid < 125) {
        const int sg = tid / 25, jq = tid % 25;
        const int t0 = sg * 10;
        float4 sacc[10];
        #pragma unroll
        for (int tt = 0; tt < 10; ++tt) sacc[tt] = make_float4(0.f,0.f,0.f,0.f);
        int at[10];
        #pragma unroll
        for (int tt = 0; tt < 10; ++tt) at[tt] = aliasS[t0+tt];
        for (int k = 0; k < D; k += 2) {
            float4 wa = *(const float4*)&w2[(size_t)k*D + jq*4];
            float4 wb = *(const float4*)&w2[(size_t)(k+1)*D + jq*4];
            #pragma unroll
            for (int tt = 0; tt < 10; ++tt) {
                float2 a = *(const float2*)&hS[at[tt]*D + k];
                sacc[tt].x += a.x*wa.x + a.y*wb.x;
                sacc[tt].y += a.x*wa.y + a.y*wb.y;
                sacc[tt].z += a.x*wa.z + a.y*wb.z;
                sacc[tt].w += a.x*wa.w + a.y*wb.w;
            }
        }
        #pragma unroll
        for (int tt = 0; tt < 10; ++tt)
            *(float4*)&R1[(t0+tt)*D + jq*4] = sacc[tt];
    } else if (tid >= 128 && tid < 153) {
        const int jq = tid - 128;
        const int lid = rmidx;
        float4 acc = make_float4(0.f,0.f,0.f,0.f);
        for (int k = 0; k < D; k += 2) {
            float4 wa = *(const float4*)&w1[(size_t)k*D + jq*4];
            float4 wb = *(const float4*)&w1[(size_t)(k+1)*D + jq*4];
            float2 a = *(const float2*)&hS[lid*D + k];
            acc.x += a.x*wa.x + a.y*wb.x;
            acc.y += a.x*wa.y + a.y*wb.y;
            acc.z += a.x*wa.z + a.y*wb.z;
            acc.w += a.x*wa.w + a.y*wb.w;
        }
        *(float4*)&lastWS[jq*4] = acc;
    }
    __syncthreads();

    // ---- P9: coef[t] = mask[t] * sum_k v[k]*sigmoid(lastW[k]+seqW[t][k]+nb[k])
    if (tid < T) {
        float s = 0.f;
        #pragma unroll 4
        for (int k = 0; k < D; ++k) {
            float x = lastWS[k] + R1[tid*D + k] + nbS[k];
            s += vS[k] * sigf(x);
        }
        coefS[tid] = s * maskS[tid];
    }
    __syncthreads();
    // ---- P10: ma = [sum_t coef[t]*h'[alias[t]], lastW] ----
    if (tid < 25) {
        float4 acc = make_float4(0.f,0.f,0.f,0.f);
        #pragma unroll 5
        for (int t = 0; t < T; ++t) {
            float c = coefS[t];
            float4 hh = *(const float4*)&hS[aliasS[t]*D + tid*4];
            acc.x += c*hh.x; acc.y += c*hh.y; acc.z += c*hh.z; acc.w += c*hh.w;
        }
        *(float4*)&maS[tid*4] = acc;
    } else if (tid >= 32 && tid < 57) {
        int j4 = tid - 32;
        *(float4*)&maS[D + j4*4] = *(const float4*)&lastWS[j4*4];
    }
    __syncthreads();
    // ---- P11: y1[b] = ma @ B_mat ----
    if (tid < 25) {
        float4 acc = make_float4(0.f,0.f,0.f,0.f);
        #pragma unroll 4
        for (int k = 0; k < 2*D; ++k) {
            float a = maS[k];
            float4 w = *(const float4*)&Bm[(size_t)k*D + tid*4];
            acc.x += a*w.x; acc.y += a*w.y; acc.z += a*w.z; acc.w += a*w.w;
        }
        *(float4*)&y1[(size_t)b*D + tid*4] = acc;
    }
}

// ===========================================================================
// logits[512, 99999] = y1[512,100] @ emb[1:,:]^T
// B-stationary: one block per 128-col n-tile x 256-row m-half; B tile staged
// once (52.8 KB LDS), 2 m-chunks of 128 rows; A (y1) from L2 broadcast loads.
// Bs columns stored PERMUTED: col (h*64 + j*16 + tx) at slot (h*64 + tx*4 + j)
// so each thread's 8 owned columns are two ds_read_b128 (was 8 scalar reads
// per kk -> 4x fewer LDS issue cycles), while stores keep the 64 B-contiguous
// {tx,+16,+32,+48} instruction pattern (float4 stores impossible: NOUT=99999
// makes 3/4 of out rows 16B-misaligned).
// ===========================================================================
#define LDB 132   // divisible by 4 -> b128-aligned rows; 52.8 KB total

#define GB_COMPUTE(Ab, kbase) do {                                            \
    _Pragma("unroll")                                                         \
    for (int kk = 0; kk < 4; ++kk) {                                          \
        float4 b0 = *(const float4*)&Bs[(kbase + kk)*LDB + tx*4];             \
        float4 b1 = *(const float4*)&Bs[(kbase + kk)*LDB + 64 + tx*4];        \
        _Pragma("unroll")                                                     \
        for (int i = 0; i < 8; ++i) {                                         \
            float a_ = kk==0 ? Ab[i].x : kk==1 ? Ab[i].y :                    \
                       kk==2 ? Ab[i].z : Ab[i].w;                             \
            acc[i][0] += a_*b0.x; acc[i][1] += a_*b0.y;                       \
            acc[i][2] += a_*b0.z; acc[i][3] += a_*b0.w;                       \
            acc[i][4] += a_*b1.x; acc[i][5] += a_*b1.y;                       \
            acc[i][6] += a_*b1.z; acc[i][7] += a_*b1.w;                       \
        }                                                                     \
    }                                                                         \
} while (0)

__global__ __launch_bounds__(256) void gemm_big(
    const float* __restrict__ y1,
    const float* __restrict__ emb,
    float* __restrict__ out)
{
    __shared__ float Bs[100*LDB];          // 52.8 KB
    const int tid = threadIdx.x;
    const int tx = tid & 15, ty = tid >> 4;
    const int n0 = blockIdx.x * 128;

    // stage B: cols n0..n0+127, k=0..99, transposed + column-permuted
    for (int idx = tid; idx < 128*25; idx += 256) {
        int n = idx / 25, q = idx - n*25;
        int gn = n0 + n;
        float4 vv = make_float4(0.f,0.f,0.f,0.f);
        if (gn < NOUT) vv = *(const float4*)&emb[(size_t)(gn+1)*D + q*4];
        int w = n & 63;
        int pos = (n & 64) + ((w & 15) << 2) + (w >> 4);
        Bs[(q*4+0)*LDB + pos] = vv.x;
        Bs[(q*4+1)*LDB + pos] = vv.y;
        Bs[(q*4+2)*LDB + pos] = vv.z;
        Bs[(q*4+3)*LDB + pos] = vv.w;
    }
    __syncthreads();

    float acc[8][8];
    float4 A0[8], A1[8];

    #pragma unroll 1
    for (int mc = 0; mc < 2; ++mc) {
        const int m0 = blockIdx.y * 256 + mc * 128;

        #pragma unroll
        for (int i = 0; i < 8; ++i)
            #pragma unroll
            for (int j = 0; j < 8; ++j) acc[i][j] = 0.f;

        #pragma unroll
        for (int i = 0; i < 8; ++i)
            A0[i] = *(const float4*)&y1[(size_t)(m0 + ty + i*16)*D + 0];

        int k = 0;
        #pragma unroll 1
        for (int it = 0; it < 12; ++it, k += 8) {
            #pragma unroll
            for (int i = 0; i < 8; ++i)
                A1[i] = *(const float4*)&y1[(size_t)(m0 + ty + i*16)*D + k + 4];
            GB_COMPUTE(A0, k);
            #pragma unroll
            for (int i = 0; i < 8; ++i)
                A0[i] = *(const float4*)&y1[(size_t)(m0 + ty + i*16)*D + k + 8];
            GB_COMPUTE(A1, k + 4);
        }
        GB_COMPUTE(A0, 96);   // k = 96..99 tail

        // store: each instr = 16 consecutive lanes -> 64 B contiguous/row
        #pragma unroll
        for (int i = 0; i < 8; ++i) {
            size_t row = (size_t)(m0 + ty + i*16) * NOUT;
            #pragma unroll
            for (int h = 0; h < 2; ++h)
                #pragma unroll
                for (int q = 0; q < 4; ++q) {
                    int n = n0 + h*64 + q*16 + tx;
                    if (n < NOUT) out[row + n] = acc[i][h*4+q];
                }
        }
    }
}

// ---------------------------------------------------------------------------
extern "C" void kernel_launch(void* const* d_in, const int* in_sizes, int n_in,
                              void* d_out, int out_size, void* d_ws, size_t ws_size,
                              hipStream_t stream)
{
    const float* adj_in  = (const float*)d_in[0];
    const float* adj_out = (const float*)d_in[1];
    const float* mask    = (const float*)d_in[2];
    const int*   item    = (const int*)  d_in[3];
    const int*   alias_  = (const int*)  d_in[4];
    const float* emb     = (const float*)d_in[6];
    const float* W_in    = (const float*)d_in[7];
    const float* b_in    = (const float*)d_in[8];
    const float* W_out   = (const float*)d_in[9];
    const float* b_out   = (const float*)d_in[10];
    const float* gate_k  = (const float*)d_in[11];
    const float* gate_b  = (const float*)d_in[12];
    const float* cand_k  = (const float*)d_in[13];
    const float* cand_b  = (const float*)d_in[14];
    const float* w1      = (const float*)d_in[15];
    const float* w2      = (const float*)d_in[16];
    const float* v       = (const float*)d_in[17];
    const float* nb      = (const float*)d_in[18];
    const float* Bm      = (const float*)d_in[19];
    float* out = (float*)d_out;
    float* y1  = (float*)d_ws;   // [512,100]

    ggnn_fused<<<BB, 256, 0, stream>>>(
        adj_in, adj_out, mask, item, alias_, emb,
        W_in, b_in, W_out, b_out, gate_k, gate_b, cand_k, cand_b,
        w1, w2, v, nb, Bm, y1);

    gemm_big<<<dim3((NOUT + 127)/128, 2), 256, 0, stream>>>(y1, emb, out);
}

// Round 7
// 635.460 us; speedup vs baseline: 1.1612x; 1.1612x over previous
//
#include <hip/hip_runtime.h>
#include <math.h>

#define D 100
#define T 50
#define BB 512
#define NOUT 99999

__device__ __forceinline__ float sigf(float x) { return 1.f / (1.f + expf(-x)); }

// ===========================================================================
// Fused per-batch GGNN + attention kernel. One block per batch (512 blocks).
// LDS: hS (h, later h'), R1 (X1 -> a_in -> r*h -> seqW), R2 (X2 -> a_out -> u)
// Weight-GEMM phases register-tiled over t (10/5-row tiles): weight quads
// loaded once per t-group. NO software prefetch anywhere: VGPR must stay
// <= 128 (measured cliff: 128 -> 2 blocks/CU @ 240us; 144 -> 1 block/CU
// @ 414us; 228 -> 1 block @ 275us). The {2 blocks + prefetch} quadrant is
// unreachable within the register budget.
// ===========================================================================
__global__ __launch_bounds__(256) void ggnn_fused(
    const float* __restrict__ adj_in, const float* __restrict__ adj_out,
    const float* __restrict__ mask,   const int* __restrict__ item,
    const int* __restrict__ alias_,   const float* __restrict__ emb,
    const float* __restrict__ W_in,   const float* __restrict__ b_in,
    const float* __restrict__ W_out,  const float* __restrict__ b_out,
    const float* __restrict__ gate_k, const float* __restrict__ gate_b,
    const float* __restrict__ cand_k, const float* __restrict__ cand_b,
    const float* __restrict__ w1,     const float* __restrict__ w2,
    const float* __restrict__ v,      const float* __restrict__ nb,
    const float* __restrict__ Bm,     float* __restrict__ y1)
{
    __shared__ float hS[T*D];      // 20 KB
    __shared__ float R1[T*D];      // 20 KB
    __shared__ float R2[T*D];      // 20 KB
    __shared__ float maskS[T+2], vS[D], nbS[D], lastWS[D], coefS[T+2], maS[2*D];
    __shared__ int aliasS[T+2];
    __shared__ int rmidx;

    const int b = blockIdx.x, tid = threadIdx.x;
    const size_t bT = (size_t)b * T;

    // ---- P0: small stages ----
    if (tid < T) {
        aliasS[tid] = alias_[bT + tid];
        maskS[tid]  = mask[bT + tid];
    }
    if (tid >= 64 && tid < 64 + D) {
        int k = tid - 64;
        vS[k] = v[k]; nbS[k] = nb[k];
    }
    // ---- P1: h = emb[item] ----
    for (int idx = tid; idx < T*25; idx += 256) {
        int t = idx / 25, q = idx - t*25;
        int node = item[bT + t];
        *(float4*)&hS[t*D + q*4] = *(const float4*)&emb[(size_t)node*D + q*4];
    }
    __syncthreads();
    if (tid == 0) {
        float s = 0.f;
        for (int t = 0; t < T; ++t) s += maskS[t];
        rmidx = aliasS[(int)s - 1];
    }

    // role decode for the 250 active weight-GEMM threads
    const bool act250 = tid < 250;
    const int tg50  = tid / 50;      // 0..4 valid  (t-group of 10)
    const int rem50 = tid % 50;
    const int cg25  = tid / 25;      // 0..9 valid  (t-group of 5)
    const int jq25  = tid % 25;

    // ---- P2: X1 = h@W_in+b_in -> R1 ; X2 = h@W_out+b_out -> R2 ----
    // thread = (which, jq, tgroup of 10 t); weight quad loaded once per 10 t
    if (act250) {
        const int which = rem50 / 25, jq = rem50 % 25;
        const int t0 = tg50 * 10;
        const float* W  = which ? W_out : W_in;
        const float* bb = which ? b_out : b_in;
        float4 binit = *(const float4*)&bb[jq*4];
        float4 acc[10];
        #pragma unroll
        for (int tt = 0; tt < 10; ++tt) acc[tt] = binit;
        for (int k = 0; k < D; k += 2) {
            float4 wa = *(const float4*)&W[k*D + jq*4];
            float4 wb = *(const float4*)&W[(k+1)*D + jq*4];
            #pragma unroll
            for (int tt = 0; tt < 10; ++tt) {
                float2 a = *(const float2*)&hS[(t0+tt)*D + k];
                acc[tt].x += a.x*wa.x + a.y*wb.x;
                acc[tt].y += a.x*wa.y + a.y*wb.y;
                acc[tt].z += a.x*wa.z + a.y*wb.z;
                acc[tt].w += a.x*wa.w + a.y*wb.w;
            }
        }
        float* dst = which ? R2 : R1;
        #pragma unroll
        for (int tt = 0; tt < 10; ++tt)
            *(float4*)&dst[(t0+tt)*D + jq*4] = acc[tt];
    }
    __syncthreads();

    // ---- P3: a_in = adj_in@X1, a_out = adj_out@X2 (into regs) ----
    float4 eacc[10];
    if (act250) {
        const int which = rem50 / 25, jq = rem50 % 25;
        const int t0 = tg50 * 10;
        const float* adj = which ? adj_out : adj_in;
        const float* Xs  = which ? R2 : R1;
        #pragma unroll
        for (int tt = 0; tt < 10; ++tt) eacc[tt] = make_float4(0.f,0.f,0.f,0.f);
        #pragma unroll 2
        for (int s = 0; s < T; ++s) {
            float4 x = *(const float4*)&Xs[s*D + jq*4];
            const float* ap = &adj[(bT + t0)*T + s];
            #pragma unroll
            for (int tt = 0; tt < 10; ++tt) {
                float a = ap[tt*T];
                eacc[tt].x += a*x.x; eacc[tt].y += a*x.y;
                eacc[tt].z += a*x.z; eacc[tt].w += a*x.w;
            }
        }
    }
    __syncthreads();                 // all X reads done
    // ---- P3b: write a_in -> R1, a_out -> R2 ----
    if (act250) {
        const int which = rem50 / 25, jq = rem50 % 25;
        const int t0 = tg50 * 10;
        float* dst = which ? R2 : R1;
        #pragma unroll
        for (int tt = 0; tt < 10; ++tt)
            *(float4*)&dst[(t0+tt)*D + jq*4] = eacc[tt];
    }
    __syncthreads();

    // ---- P4: gates = sigmoid([a_in|a_out|h] @ gate_k + gate_b) into regs ----
    // thread = (nq 0..49, tgroup of 10 t); 6 weight quads per k-pair, 10 rows
    float4 gacc[10];
    if (act250) {
        const int nq = rem50;
        const int t0 = tg50 * 10;
        float4 ginit = *(const float4*)&gate_b[nq*4];
        #pragma unroll
        for (int tt = 0; tt < 10; ++tt) gacc[tt] = ginit;
        for (int k = 0; k < D; k += 2) {
            float4 g0a = *(const float4*)&gate_k[(size_t)k*200 + nq*4];
            float4 g0b = *(const float4*)&gate_k[(size_t)(k+1)*200 + nq*4];
            float4 g1a = *(const float4*)&gate_k[(size_t)(k+100)*200 + nq*4];
            float4 g1b = *(const float4*)&gate_k[(size_t)(k+101)*200 + nq*4];
            float4 g2a = *(const float4*)&gate_k[(size_t)(k+200)*200 + nq*4];
            float4 g2b = *(const float4*)&gate_k[(size_t)(k+201)*200 + nq*4];
            #pragma unroll
            for (int tt = 0; tt < 10; ++tt) {
                float2 a0 = *(const float2*)&R1[(t0+tt)*D + k];
                float2 a1 = *(const float2*)&R2[(t0+tt)*D + k];
                float2 a2 = *(const float2*)&hS[(t0+tt)*D + k];
                gacc[tt].x += a0.x*g0a.x + a0.y*g0b.x + a1.x*g1a.x + a1.y*g1b.x + a2.x*g2a.x + a2.y*g2b.x;
                gacc[tt].y += a0.x*g0a.y + a0.y*g0b.y + a1.x*g1a.y + a1.y*g1b.y + a2.x*g2a.y + a2.y*g2b.y;
                gacc[tt].z += a0.x*g0a.z + a0.y*g0b.z + a1.x*g1a.z + a1.y*g1b.z + a2.x*g2a.z + a2.y*g2b.z;
                gacc[tt].w += a0.x*g0a.w + a0.y*g0b.w + a1.x*g1a.w + a1.y*g1b.w + a2.x*g2a.w + a2.y*g2b.w;
            }
        }
        #pragma unroll
        for (int tt = 0; tt < 10; ++tt) {
            gacc[tt].x = sigf(gacc[tt].x); gacc[tt].y = sigf(gacc[tt].y);
            gacc[tt].z = sigf(gacc[tt].z); gacc[tt].w = sigf(gacc[tt].w);
        }
    }

    // ---- P5a: cand partial (segments a_in, a_out) into regs ----
    // thread = (jq 0..24, tgroup of 5 t)
    float4 cacc[5];
    if (act250) {
        const int t0 = cg25 * 5;
        float4 cinit = *(const float4*)&cand_b[jq25*4];
        #pragma unroll
        for (int tt = 0; tt < 5; ++tt) cacc[tt] = cinit;
        for (int k = 0; k < D; k += 2) {
            float4 c0a = *(const float4*)&cand_k[(size_t)k*D + jq25*4];
            float4 c0b = *(const float4*)&cand_k[(size_t)(k+1)*D + jq25*4];
            float4 c1a = *(const float4*)&cand_k[(size_t)(k+100)*D + jq25*4];
            float4 c1b = *(const float4*)&cand_k[(size_t)(k+101)*D + jq25*4];
            #pragma unroll
            for (int tt = 0; tt < 5; ++tt) {
                float2 a0 = *(const float2*)&R1[(t0+tt)*D + k];
                float2 a1 = *(const float2*)&R2[(t0+tt)*D + k];
                cacc[tt].x += a0.x*c0a.x + a0.y*c0b.x + a1.x*c1a.x + a1.y*c1b.x;
                cacc[tt].y += a0.x*c0a.y + a0.y*c0b.y + a1.x*c1a.y + a1.y*c1b.y;
                cacc[tt].z += a0.x*c0a.z + a0.y*c0b.z + a1.x*c1a.z + a1.y*c1b.z;
                cacc[tt].w += a0.x*c0a.w + a0.y*c0b.w + a1.x*c1a.w + a1.y*c1b.w;
            }
        }
    }
    __syncthreads();                 // R1/R2 (a_in/a_out) reads done

    // ---- P5b: r-owners write r*h -> R1 ; u-owners write u -> R2 ----
    if (act250) {
        const int nq = rem50;
        const int t0 = tg50 * 10;
        if (nq < 25) {
            #pragma unroll
            for (int tt = 0; tt < 10; ++tt) {
                float4 hh = *(const float4*)&hS[(t0+tt)*D + nq*4];
                float4 g = gacc[tt];
                float4 o; o.x = g.x*hh.x; o.y = g.y*hh.y; o.z = g.z*hh.z; o.w = g.w*hh.w;
                *(float4*)&R1[(t0+tt)*D + nq*4] = o;
            }
        } else {
            #pragma unroll
            for (int tt = 0; tt < 10; ++tt)
                *(float4*)&R2[(t0+tt)*D + (nq-25)*4] = gacc[tt];
        }
    }
    __syncthreads();

    // ---- P5c: cand segment r*h + tanh; fused P7: h' = u*h+(1-u)*c -> hS ----
    if (act250) {
        const int t0 = cg25 * 5;
        for (int k = 0; k < D; k += 2) {
            float4 c2a = *(const float4*)&cand_k[(size_t)(k+200)*D + jq25*4];
            float4 c2b = *(const float4*)&cand_k[(size_t)(k+201)*D + jq25*4];
            #pragma unroll
            for (int tt = 0; tt < 5; ++tt) {
                float2 rh = *(const float2*)&R1[(t0+tt)*D + k];
                cacc[tt].x += rh.x*c2a.x + rh.y*c2b.x;
                cacc[tt].y += rh.x*c2a.y + rh.y*c2b.y;
                cacc[tt].z += rh.x*c2a.z + rh.y*c2b.z;
                cacc[tt].w += rh.x*c2a.w + rh.y*c2b.w;
            }
        }
        #pragma unroll
        for (int tt = 0; tt < 5; ++tt) {
            float4 c4;
            c4.x = tanhf(cacc[tt].x); c4.y = tanhf(cacc[tt].y);
            c4.z = tanhf(cacc[tt].z); c4.w = tanhf(cacc[tt].w);
            float4 u4 = *(const float4*)&R2[(t0+tt)*D + jq25*4];
            float4 hh = *(const float4*)&hS[(t0+tt)*D + jq25*4];
            float4 o;
            o.x = u4.x*hh.x + (1.f-u4.x)*c4.x;
            o.y = u4.y*hh.y + (1.f-u4.y)*c4.y;
            o.z = u4.z*hh.z + (1.f-u4.z)*c4.z;
            o.w = u4.w*hh.w + (1.f-u4.w)*c4.w;
            *(float4*)&hS[(t0+tt)*D + jq25*4] = o;
        }
    }
    __syncthreads();

    // ---- P8: seqW[t] = h'[alias[t]] @ w2 -> R1 ; lastW = h'[rmidx] @ w1 ----
    if (tid < 125) {
        const int sg = tid / 25, jq = tid % 25;
        const int t0 = sg * 10;
        float4 sacc[10];
        #pragma unroll
        for (int tt = 0; tt < 10; ++tt) sacc[tt] = make_float4(0.f,0.f,0.f,0.f);
        int at[10];
        #pragma unroll
        for (int tt = 0; tt < 10; ++tt) at[tt] = aliasS[t0+tt];
        for (int k = 0; k < D; k += 2) {
            float4 wa = *(const float4*)&w2[(size_t)k*D + jq*4];
            float4 wb = *(const float4*)&w2[(size_t)(k+1)*D + jq*4];
            #pragma unroll
            for (int tt = 0; tt < 10; ++tt) {
                float2 a = *(const float2*)&hS[at[tt]*D + k];
                sacc[tt].x += a.x*wa.x + a.y*wb.x;
                sacc[tt].y += a.x*wa.y + a.y*wb.y;
                sacc[tt].z += a.x*wa.z + a.y*wb.z;
                sacc[tt].w += a.x*wa.w + a.y*wb.w;
            }
        }
        #pragma unroll
        for (int tt = 0; tt < 10; ++tt)
            *(float4*)&R1[(t0+tt)*D + jq*4] = sacc[tt];
    } else if (tid >= 128 && tid < 153) {
        const int jq = tid - 128;
        const int lid = rmidx;
        float4 acc = make_float4(0.f,0.f,0.f,0.f);
        for (int k = 0; k < D; k += 2) {
            float4 wa = *(const float4*)&w1[(size_t)k*D + jq*4];
            float4 wb = *(const float4*)&w1[(size_t)(k+1)*D + jq*4];
            float2 a = *(const float2*)&hS[lid*D + k];
            acc.x += a.x*wa.x + a.y*wb.x;
            acc.y += a.x*wa.y + a.y*wb.y;
            acc.z += a.x*wa.z + a.y*wb.z;
            acc.w += a.x*wa.w + a.y*wb.w;
        }
        *(float4*)&lastWS[jq*4] = acc;
    }
    __syncthreads();

    // ---- P9: coef[t] = mask[t] * sum_k v[k]*sigmoid(lastW[k]+seqW[t][k]+nb[k])
    if (tid < T) {
        float s = 0.f;
        #pragma unroll 4
        for (int k = 0; k < D; ++k) {
            float x = lastWS[k] + R1[tid*D + k] + nbS[k];
            s += vS[k] * sigf(x);
        }
        coefS[tid] = s * maskS[tid];
    }
    __syncthreads();
    // ---- P10: ma = [sum_t coef[t]*h'[alias[t]], lastW] ----
    if (tid < 25) {
        float4 acc = make_float4(0.f,0.f,0.f,0.f);
        #pragma unroll 5
        for (int t = 0; t < T; ++t) {
            float c = coefS[t];
            float4 hh = *(const float4*)&hS[aliasS[t]*D + tid*4];
            acc.x += c*hh.x; acc.y += c*hh.y; acc.z += c*hh.z; acc.w += c*hh.w;
        }
        *(float4*)&maS[tid*4] = acc;
    } else if (tid >= 32 && tid < 57) {
        int j4 = tid - 32;
        *(float4*)&maS[D + j4*4] = *(const float4*)&lastWS[j4*4];
    }
    __syncthreads();
    // ---- P11: y1[b] = ma @ B_mat ----
    if (tid < 25) {
        float4 acc = make_float4(0.f,0.f,0.f,0.f);
        #pragma unroll 4
        for (int k = 0; k < 2*D; ++k) {
            float a = maS[k];
            float4 w = *(const float4*)&Bm[(size_t)k*D + tid*4];
            acc.x += a*w.x; acc.y += a*w.y; acc.z += a*w.z; acc.w += a*w.w;
        }
        *(float4*)&y1[(size_t)b*D + tid*4] = acc;
    }
}

// ===========================================================================
// logits[512, 99999] = y1[512,100] @ emb[1:,:]^T
// B-stationary: one block per 128-col n-tile x 256-row m-half; B tile staged
// once (52.8 KB LDS), 2 m-chunks of 128 rows; A (y1) from L2 broadcast loads.
// Bs columns stored PERMUTED: col (h*64 + j*16 + tx) at slot (h*64 + tx*4 + j)
// so each thread's 8 owned columns are two ds_read_b128 (was 8 scalar reads
// per kk -> 4x fewer LDS issue cycles), while stores keep the 64 B-contiguous
// {tx,+16,+32,+48} instruction pattern (float4 stores impossible: NOUT=99999
// makes 3/4 of out rows 16B-misaligned).
// ===========================================================================
#define LDB 132   // divisible by 4 -> b128-aligned rows; 52.8 KB total

#define GB_COMPUTE(Ab, kbase) do {                                            \
    _Pragma("unroll")                                                         \
    for (int kk = 0; kk < 4; ++kk) {                                          \
        float4 b0 = *(const float4*)&Bs[(kbase + kk)*LDB + tx*4];             \
        float4 b1 = *(const float4*)&Bs[(kbase + kk)*LDB + 64 + tx*4];        \
        _Pragma("unroll")                                                     \
        for (int i = 0; i < 8; ++i) {                                         \
            float a_ = kk==0 ? Ab[i].x : kk==1 ? Ab[i].y :                    \
                       kk==2 ? Ab[i].z : Ab[i].w;                             \
            acc[i][0] += a_*b0.x; acc[i][1] += a_*b0.y;                       \
            acc[i][2] += a_*b0.z; acc[i][3] += a_*b0.w;                       \
            acc[i][4] += a_*b1.x; acc[i][5] += a_*b1.y;                       \
            acc[i][6] += a_*b1.z; acc[i][7] += a_*b1.w;                       \
        }                                                                     \
    }                                                                         \
} while (0)

__global__ __launch_bounds__(256) void gemm_big(
    const float* __restrict__ y1,
    const float* __restrict__ emb,
    float* __restrict__ out)
{
    __shared__ float Bs[100*LDB];          // 52.8 KB
    const int tid = threadIdx.x;
    const int tx = tid & 15, ty = tid >> 4;
    const int n0 = blockIdx.x * 128;

    // stage B: cols n0..n0+127, k=0..99, transposed + column-permuted
    for (int idx = tid; idx < 128*25; idx += 256) {
        int n = idx / 25, q = idx - n*25;
        int gn = n0 + n;
        float4 vv = make_float4(0.f,0.f,0.f,0.f);
        if (gn < NOUT) vv = *(const float4*)&emb[(size_t)(gn+1)*D + q*4];
        int w = n & 63;
        int pos = (n & 64) + ((w & 15) << 2) + (w >> 4);
        Bs[(q*4+0)*LDB + pos] = vv.x;
        Bs[(q*4+1)*LDB + pos] = vv.y;
        Bs[(q*4+2)*LDB + pos] = vv.z;
        Bs[(q*4+3)*LDB + pos] = vv.w;
    }
    __syncthreads();

    float acc[8][8];
    float4 A0[8], A1[8];

    #pragma unroll 1
    for (int mc = 0; mc < 2; ++mc) {
        const int m0 = blockIdx.y * 256 + mc * 128;

        #pragma unroll
        for (int i = 0; i < 8; ++i)
            #pragma unroll
            for (int j = 0; j < 8; ++j) acc[i][j] = 0.f;

        #pragma unroll
        for (int i = 0; i < 8; ++i)
            A0[i] = *(const float4*)&y1[(size_t)(m0 + ty + i*16)*D + 0];

        int k = 0;
        #pragma unroll 1
        for (int it = 0; it < 12; ++it, k += 8) {
            #pragma unroll
            for (int i = 0; i < 8; ++i)
                A1[i] = *(const float4*)&y1[(size_t)(m0 + ty + i*16)*D + k + 4];
            GB_COMPUTE(A0, k);
            #pragma unroll
            for (int i = 0; i < 8; ++i)
                A0[i] = *(const float4*)&y1[(size_t)(m0 + ty + i*16)*D + k + 8];
            GB_COMPUTE(A1, k + 4);
        }
        GB_COMPUTE(A0, 96);   // k = 96..99 tail

        // store: each instr = 16 consecutive lanes -> 64 B contiguous/row
        #pragma unroll
        for (int i = 0; i < 8; ++i) {
            size_t row = (size_t)(m0 + ty + i*16) * NOUT;
            #pragma unroll
            for (int h = 0; h < 2; ++h)
                #pragma unroll
                for (int q = 0; q < 4; ++q) {
                    int n = n0 + h*64 + q*16 + tx;
                    if (n < NOUT) out[row + n] = acc[i][h*4+q];
                }
        }
    }
}

// ---------------------------------------------------------------------------
extern "C" void kernel_launch(void* const* d_in, const int* in_sizes, int n_in,
                              void* d_out, int out_size, void* d_ws, size_t ws_size,
                              hipStream_t stream)
{
    const float* adj_in  = (const float*)d_in[0];
    const float* adj_out = (const float*)d_in[1];
    const float* mask    = (const float*)d_in[2];
    const int*   item    = (const int*)  d_in[3];
    const int*   alias_  = (const int*)  d_in[4];
    const float* emb     = (const float*)d_in[6];
    const float* W_in    = (const float*)d_in[7];
    const float* b_in    = (const float*)d_in[8];
    const float* W_out   = (const float*)d_in[9];
    const float* b_out   = (const float*)d_in[10];
    const float* gate_k  = (const float*)d_in[11];
    const float* gate_b  = (const float*)d_in[12];
    const float* cand_k  = (const float*)d_in[13];
    const float* cand_b  = (const float*)d_in[14];
    const float* w1      = (const float*)d_in[15];
    const float* w2      = (const float*)d_in[16];
    const float* v       = (const float*)d_in[17];
    const float* nb      = (const float*)d_in[18];
    const float* Bm      = (const float*)d_in[19];
    float* out = (float*)d_out;
    float* y1  = (float*)d_ws;   // [512,100]

    ggnn_fused<<<BB, 256, 0, stream>>>(
        adj_in, adj_out, mask, item, alias_, emb,
        W_in, b_in, W_out, b_out, gate_k, gate_b, cand_k, cand_b,
        w1, w2, v, nb, Bm, y1);

    gemm_big<<<dim3((NOUT + 127)/128, 2), 256, 0, stream>>>(y1, emb, out);
}

// Round 8
// 629.615 us; speedup vs baseline: 1.1720x; 1.0093x over previous
//
#include <hip/hip_runtime.h>
#include <math.h>

#define D 100
#define T 50
#define BB 512
#define NOUT 99999

__device__ __forceinline__ float sigf(float x) { return 1.f / (1.f + expf(-x)); }

// ===========================================================================
// Fused per-batch GGNN + attention kernel. One 512-THREAD block per batch.
// 512 blocks / 256 CU = 2 blocks/CU; 512-thread blocks -> 16 waves/CU
// (was 8 with 256-thread blocks) -> 2x latency hiding TLP at the same LDS.
// Per-thread tiles halve (t-groups of 5) so VGPR stays under the 128 cliff
// (measured: 128 -> 2 blocks/CU; >128 -> 1 block/CU, net loss).
// P5a/P5c/P8 use lane-pair K-split + shfl_xor(1) reduction to keep all 500
// worker threads busy with wave-uniform control flow.
// ===========================================================================
__global__ __launch_bounds__(512, 4) void ggnn_fused(
    const float* __restrict__ adj_in, const float* __restrict__ adj_out,
    const float* __restrict__ mask,   const int* __restrict__ item,
    const int* __restrict__ alias_,   const float* __restrict__ emb,
    const float* __restrict__ W_in,   const float* __restrict__ b_in,
    const float* __restrict__ W_out,  const float* __restrict__ b_out,
    const float* __restrict__ gate_k, const float* __restrict__ gate_b,
    const float* __restrict__ cand_k, const float* __restrict__ cand_b,
    const float* __restrict__ w1,     const float* __restrict__ w2,
    const float* __restrict__ v,      const float* __restrict__ nb,
    const float* __restrict__ Bm,     float* __restrict__ y1)
{
    __shared__ float hS[T*D];      // 20 KB
    __shared__ float R1[T*D];      // 20 KB
    __shared__ float R2[T*D];      // 20 KB
    __shared__ float maskS[T+2], vS[D], nbS[D], lastWS[D], coefS[T+2], maS[2*D];
    __shared__ int aliasS[T+2];
    __shared__ int rmidx;

    const int b = blockIdx.x, tid = threadIdx.x;
    const size_t bT = (size_t)b * T;

    // ---- P0: small stages ----
    if (tid < T) {
        aliasS[tid] = alias_[bT + tid];
        maskS[tid]  = mask[bT + tid];
    }
    if (tid >= 64 && tid < 64 + D) {
        int k = tid - 64;
        vS[k] = v[k]; nbS[k] = nb[k];
    }
    // ---- P1: h = emb[item] ----
    for (int idx = tid; idx < T*25; idx += 512) {
        int t = idx / 25, q = idx - t*25;
        int node = item[bT + t];
        *(float4*)&hS[t*D + q*4] = *(const float4*)&emb[(size_t)node*D + q*4];
    }
    __syncthreads();
    if (tid == 0) {
        float s = 0.f;
        for (int t = 0; t < T; ++t) s += maskS[t];
        rmidx = aliasS[(int)s - 1];
    }

    const bool act500 = tid < 500;

    // ---- P2: X1 = h@W_in+b_in -> R1 ; X2 = h@W_out+b_out -> R2 ----
    // thread = (which = tid/250, jq = rem%25, t-group of 5)
    if (act500) {
        const int which = tid / 250, rem = tid % 250;
        const int jq = rem % 25, t0 = (rem / 25) * 5;
        const float* W  = which ? W_out : W_in;
        const float* bb = which ? b_out : b_in;
        float4 binit = *(const float4*)&bb[jq*4];
        float4 acc[5];
        #pragma unroll
        for (int tt = 0; tt < 5; ++tt) acc[tt] = binit;
        for (int k = 0; k < D; k += 2) {
            float4 wa = *(const float4*)&W[k*D + jq*4];
            float4 wb = *(const float4*)&W[(k+1)*D + jq*4];
            #pragma unroll
            for (int tt = 0; tt < 5; ++tt) {
                float2 a = *(const float2*)&hS[(t0+tt)*D + k];
                acc[tt].x += a.x*wa.x + a.y*wb.x;
                acc[tt].y += a.x*wa.y + a.y*wb.y;
                acc[tt].z += a.x*wa.z + a.y*wb.z;
                acc[tt].w += a.x*wa.w + a.y*wb.w;
            }
        }
        float* dst = which ? R2 : R1;
        #pragma unroll
        for (int tt = 0; tt < 5; ++tt)
            *(float4*)&dst[(t0+tt)*D + jq*4] = acc[tt];
    }
    __syncthreads();

    // ---- P3: a_in = adj_in@X1, a_out = adj_out@X2 (into regs) ----
    float4 eacc[5];
    if (act500) {
        const int which = tid / 250, rem = tid % 250;
        const int jq = rem % 25, t0 = (rem / 25) * 5;
        const float* adj = which ? adj_out : adj_in;
        const float* Xs  = which ? R2 : R1;
        #pragma unroll
        for (int tt = 0; tt < 5; ++tt) eacc[tt] = make_float4(0.f,0.f,0.f,0.f);
        #pragma unroll 2
        for (int s = 0; s < T; ++s) {
            float4 x = *(const float4*)&Xs[s*D + jq*4];
            const float* ap = &adj[(bT + t0)*T + s];
            #pragma unroll
            for (int tt = 0; tt < 5; ++tt) {
                float a = ap[tt*T];
                eacc[tt].x += a*x.x; eacc[tt].y += a*x.y;
                eacc[tt].z += a*x.z; eacc[tt].w += a*x.w;
            }
        }
    }
    __syncthreads();                 // all X reads done
    // ---- P3b: write a_in -> R1, a_out -> R2 ----
    if (act500) {
        const int which = tid / 250, rem = tid % 250;
        const int jq = rem % 25, t0 = (rem / 25) * 5;
        float* dst = which ? R2 : R1;
        #pragma unroll
        for (int tt = 0; tt < 5; ++tt)
            *(float4*)&dst[(t0+tt)*D + jq*4] = eacc[tt];
    }
    __syncthreads();

    // ---- P4: gates = sigmoid([a_in|a_out|h] @ gate_k + gate_b) into regs ----
    // thread = (nq = tid%50, t-group of 5)
    float4 gacc[5];
    if (act500) {
        const int nq = tid % 50;
        const int t0 = (tid / 50) * 5;
        float4 ginit = *(const float4*)&gate_b[nq*4];
        #pragma unroll
        for (int tt = 0; tt < 5; ++tt) gacc[tt] = ginit;
        for (int k = 0; k < D; k += 2) {
            float4 g0a = *(const float4*)&gate_k[(size_t)k*200 + nq*4];
            float4 g0b = *(const float4*)&gate_k[(size_t)(k+1)*200 + nq*4];
            float4 g1a = *(const float4*)&gate_k[(size_t)(k+100)*200 + nq*4];
            float4 g1b = *(const float4*)&gate_k[(size_t)(k+101)*200 + nq*4];
            float4 g2a = *(const float4*)&gate_k[(size_t)(k+200)*200 + nq*4];
            float4 g2b = *(const float4*)&gate_k[(size_t)(k+201)*200 + nq*4];
            #pragma unroll
            for (int tt = 0; tt < 5; ++tt) {
                float2 a0 = *(const float2*)&R1[(t0+tt)*D + k];
                float2 a1 = *(const float2*)&R2[(t0+tt)*D + k];
                float2 a2 = *(const float2*)&hS[(t0+tt)*D + k];
                gacc[tt].x += a0.x*g0a.x + a0.y*g0b.x + a1.x*g1a.x + a1.y*g1b.x + a2.x*g2a.x + a2.y*g2b.x;
                gacc[tt].y += a0.x*g0a.y + a0.y*g0b.y + a1.x*g1a.y + a1.y*g1b.y + a2.x*g2a.y + a2.y*g2b.y;
                gacc[tt].z += a0.x*g0a.z + a0.y*g0b.z + a1.x*g1a.z + a1.y*g1b.z + a2.x*g2a.z + a2.y*g2b.z;
                gacc[tt].w += a0.x*g0a.w + a0.y*g0b.w + a1.x*g1a.w + a1.y*g1b.w + a2.x*g2a.w + a2.y*g2b.w;
            }
        }
        #pragma unroll
        for (int tt = 0; tt < 5; ++tt) {
            gacc[tt].x = sigf(gacc[tt].x); gacc[tt].y = sigf(gacc[tt].y);
            gacc[tt].z = sigf(gacc[tt].z); gacc[tt].w = sigf(gacc[tt].w);
        }
    }

    // ---- P5a: cand partial (segments a_in, a_out) via lane-pair K-split ----
    // pair = (tid>>1): jq = pair%25, t-group of 5; kh = tid&1 picks segment
    float4 cacc[5];
    if (act500) {
        const int jq = (tid >> 1) % 25;
        const int t0 = ((tid >> 1) / 25) * 5;
        const int kh = tid & 1;
        const float* Ck = cand_k + (size_t)(kh ? 100 : 0) * D;
        const float* As = kh ? R2 : R1;
        float4 bq = *(const float4*)&cand_b[jq*4];
        float4 cinit = kh ? make_float4(0.f,0.f,0.f,0.f) : bq;
        #pragma unroll
        for (int tt = 0; tt < 5; ++tt) cacc[tt] = cinit;
        for (int k = 0; k < 100; k += 2) {
            float4 ca = *(const float4*)&Ck[(size_t)k*D + jq*4];
            float4 cb = *(const float4*)&Ck[(size_t)(k+1)*D + jq*4];
            #pragma unroll
            for (int tt = 0; tt < 5; ++tt) {
                float2 a = *(const float2*)&As[(t0+tt)*D + k];
                cacc[tt].x += a.x*ca.x + a.y*cb.x;
                cacc[tt].y += a.x*ca.y + a.y*cb.y;
                cacc[tt].z += a.x*ca.z + a.y*cb.z;
                cacc[tt].w += a.x*ca.w + a.y*cb.w;
            }
        }
    }
    __syncthreads();                 // R1/R2 (a_in/a_out) reads done

    // ---- P5b: r-owners write r*h -> R1 ; u-owners write u -> R2 ----
    if (act500) {
        const int nq = tid % 50;
        const int t0 = (tid / 50) * 5;
        if (nq < 25) {
            #pragma unroll
            for (int tt = 0; tt < 5; ++tt) {
                float4 hh = *(const float4*)&hS[(t0+tt)*D + nq*4];
                float4 g = gacc[tt];
                float4 o; o.x = g.x*hh.x; o.y = g.y*hh.y; o.z = g.z*hh.z; o.w = g.w*hh.w;
                *(float4*)&R1[(t0+tt)*D + nq*4] = o;
            }
        } else {
            #pragma unroll
            for (int tt = 0; tt < 5; ++tt)
                *(float4*)&R2[(t0+tt)*D + (nq-25)*4] = gacc[tt];
        }
    }
    __syncthreads();

    // ---- P5c: cand seg3 (r*h) K-split + pair-reduce + tanh + h' -> hS ----
    if (act500) {
        const int jq = (tid >> 1) % 25;
        const int t0 = ((tid >> 1) / 25) * 5;
        const int kh = tid & 1;
        const float* Ck3 = cand_k + (size_t)(200 + kh*50) * D;
        for (int k = 0; k < 50; k += 2) {
            float4 ca = *(const float4*)&Ck3[(size_t)k*D + jq*4];
            float4 cb = *(const float4*)&Ck3[(size_t)(k+1)*D + jq*4];
            #pragma unroll
            for (int tt = 0; tt < 5; ++tt) {
                float2 rh = *(const float2*)&R1[(t0+tt)*D + kh*50 + k];
                cacc[tt].x += rh.x*ca.x + rh.y*cb.x;
                cacc[tt].y += rh.x*ca.y + rh.y*cb.y;
                cacc[tt].z += rh.x*ca.z + rh.y*cb.z;
                cacc[tt].w += rh.x*ca.w + rh.y*cb.w;
            }
        }
        #pragma unroll
        for (int tt = 0; tt < 5; ++tt) {
            cacc[tt].x += __shfl_xor(cacc[tt].x, 1);
            cacc[tt].y += __shfl_xor(cacc[tt].y, 1);
            cacc[tt].z += __shfl_xor(cacc[tt].z, 1);
            cacc[tt].w += __shfl_xor(cacc[tt].w, 1);
        }
        if (!kh) {
            #pragma unroll
            for (int tt = 0; tt < 5; ++tt) {
                float4 c4;
                c4.x = tanhf(cacc[tt].x); c4.y = tanhf(cacc[tt].y);
                c4.z = tanhf(cacc[tt].z); c4.w = tanhf(cacc[tt].w);
                float4 u4 = *(const float4*)&R2[(t0+tt)*D + jq*4];
                float4 hh = *(const float4*)&hS[(t0+tt)*D + jq*4];
                float4 o;
                o.x = u4.x*hh.x + (1.f-u4.x)*c4.x;
                o.y = u4.y*hh.y + (1.f-u4.y)*c4.y;
                o.z = u4.z*hh.z + (1.f-u4.z)*c4.z;
                o.w = u4.w*hh.w + (1.f-u4.w)*c4.w;
                *(float4*)&hS[(t0+tt)*D + jq*4] = o;
            }
        }
    }
    __syncthreads();

    // ---- P8: seqW[t] = h'[alias[t]] @ w2 -> R1 (K-split pairs);
    //          lastW = h'[rmidx] @ w1 on threads 500..511 ----
    if (act500) {
        const int jq = (tid >> 1) % 25;
        const int t0 = ((tid >> 1) / 25) * 5;
        const int kh = tid & 1;
        float4 sacc[5];
        #pragma unroll
        for (int tt = 0; tt < 5; ++tt) sacc[tt] = make_float4(0.f,0.f,0.f,0.f);
        int at[5];
        #pragma unroll
        for (int tt = 0; tt < 5; ++tt) at[tt] = aliasS[t0+tt];
        const float* Wp = w2 + (size_t)(kh*50) * D;
        for (int k = 0; k < 50; k += 2) {
            float4 wa = *(const float4*)&Wp[(size_t)k*D + jq*4];
            float4 wb = *(const float4*)&Wp[(size_t)(k+1)*D + jq*4];
            #pragma unroll
            for (int tt = 0; tt < 5; ++tt) {
                float2 a = *(const float2*)&hS[at[tt]*D + kh*50 + k];
                sacc[tt].x += a.x*wa.x + a.y*wb.x;
                sacc[tt].y += a.x*wa.y + a.y*wb.y;
                sacc[tt].z += a.x*wa.z + a.y*wb.z;
                sacc[tt].w += a.x*wa.w + a.y*wb.w;
            }
        }
        #pragma unroll
        for (int tt = 0; tt < 5; ++tt) {
            sacc[tt].x += __shfl_xor(sacc[tt].x, 1);
            sacc[tt].y += __shfl_xor(sacc[tt].y, 1);
            sacc[tt].z += __shfl_xor(sacc[tt].z, 1);
            sacc[tt].w += __shfl_xor(sacc[tt].w, 1);
        }
        if (!kh) {
            #pragma unroll
            for (int tt = 0; tt < 5; ++tt)
                *(float4*)&R1[(t0+tt)*D + jq*4] = sacc[tt];
        }
    } else {
        const int u = tid - 500;
        const int lid = rmidx;
        for (int jq = u; jq < 25; jq += 12) {
            float4 acc = make_float4(0.f,0.f,0.f,0.f);
            for (int k = 0; k < D; k += 2) {
                float4 wa = *(const float4*)&w1[(size_t)k*D + jq*4];
                float4 wb = *(const float4*)&w1[(size_t)(k+1)*D + jq*4];
                float2 a = *(const float2*)&hS[lid*D + k];
                acc.x += a.x*wa.x + a.y*wb.x;
                acc.y += a.x*wa.y + a.y*wb.y;
                acc.z += a.x*wa.z + a.y*wb.z;
                acc.w += a.x*wa.w + a.y*wb.w;
            }
            *(float4*)&lastWS[jq*4] = acc;
        }
    }
    __syncthreads();

    // ---- P9: coef[t] = mask[t] * sum_k v[k]*sigmoid(lastW[k]+seqW[t][k]+nb[k])
    if (tid < T) {
        float s = 0.f;
        #pragma unroll 4
        for (int k = 0; k < D; ++k) {
            float x = lastWS[k] + R1[tid*D + k] + nbS[k];
            s += vS[k] * sigf(x);
        }
        coefS[tid] = s * maskS[tid];
    }
    __syncthreads();
    // ---- P10: ma = [sum_t coef[t]*h'[alias[t]], lastW] ----
    if (tid < 25) {
        float4 acc = make_float4(0.f,0.f,0.f,0.f);
        #pragma unroll 5
        for (int t = 0; t < T; ++t) {
            float c = coefS[t];
            float4 hh = *(const float4*)&hS[aliasS[t]*D + tid*4];
            acc.x += c*hh.x; acc.y += c*hh.y; acc.z += c*hh.z; acc.w += c*hh.w;
        }
        *(float4*)&maS[tid*4] = acc;
    } else if (tid >= 32 && tid < 57) {
        int j4 = tid - 32;
        *(float4*)&maS[D + j4*4] = *(const float4*)&lastWS[j4*4];
    }
    __syncthreads();
    // ---- P11: y1[b] = ma @ B_mat ----
    if (tid < 25) {
        float4 acc = make_float4(0.f,0.f,0.f,0.f);
        #pragma unroll 4
        for (int k = 0; k < 2*D; ++k) {
            float a = maS[k];
            float4 w = *(const float4*)&Bm[(size_t)k*D + tid*4];
            acc.x += a*w.x; acc.y += a*w.y; acc.z += a*w.z; acc.w += a*w.w;
        }
        *(float4*)&y1[(size_t)b*D + tid*4] = acc;
    }
}

// ===========================================================================
// logits[512, 99999] = y1[512,100] @ emb[1:,:]^T
// B-stationary: one block per 128-col n-tile x 256-row m-half; B tile staged
// once (52.8 KB LDS), 2 m-chunks of 128 rows; A (y1) from L2 broadcast loads.
// Bs columns stored PERMUTED: col (h*64 + j*16 + tx) at slot (h*64 + tx*4 + j)
// so each thread's 8 owned columns are two ds_read_b128 (was 8 scalar reads
// per kk -> 4x fewer LDS issue cycles), while stores keep the 64 B-contiguous
// {tx,+16,+32,+48} instruction pattern (float4 stores impossible: NOUT=99999
// makes 3/4 of out rows 16B-misaligned).
// ===========================================================================
#define LDB 132   // divisible by 4 -> b128-aligned rows; 52.8 KB total

#define GB_COMPUTE(Ab, kbase) do {                                            \
    _Pragma("unroll")                                                         \
    for (int kk = 0; kk < 4; ++kk) {                                          \
        float4 b0 = *(const float4*)&Bs[(kbase + kk)*LDB + tx*4];             \
        float4 b1 = *(const float4*)&Bs[(kbase + kk)*LDB + 64 + tx*4];        \
        _Pragma("unroll")                                                     \
        for (int i = 0; i < 8; ++i) {                                         \
            float a_ = kk==0 ? Ab[i].x : kk==1 ? Ab[i].y :                    \
                       kk==2 ? Ab[i].z : Ab[i].w;                             \
            acc[i][0] += a_*b0.x; acc[i][1] += a_*b0.y;                       \
            acc[i][2] += a_*b0.z; acc[i][3] += a_*b0.w;                       \
            acc[i][4] += a_*b1.x; acc[i][5] += a_*b1.y;                       \
            acc[i][6] += a_*b1.z; acc[i][7] += a_*b1.w;                       \
        }                                                                     \
    }                                                                         \
} while (0)

__global__ __launch_bounds__(256) void gemm_big(
    const float* __restrict__ y1,
    const float* __restrict__ emb,
    float* __restrict__ out)
{
    __shared__ float Bs[100*LDB];          // 52.8 KB
    const int tid = threadIdx.x;
    const int tx = tid & 15, ty = tid >> 4;
    const int n0 = blockIdx.x * 128;

    // stage B: cols n0..n0+127, k=0..99, transposed + column-permuted
    for (int idx = tid; idx < 128*25; idx += 256) {
        int n = idx / 25, q = idx - n*25;
        int gn = n0 + n;
        float4 vv = make_float4(0.f,0.f,0.f,0.f);
        if (gn < NOUT) vv = *(const float4*)&emb[(size_t)(gn+1)*D + q*4];
        int w = n & 63;
        int pos = (n & 64) + ((w & 15) << 2) + (w >> 4);
        Bs[(q*4+0)*LDB + pos] = vv.x;
        Bs[(q*4+1)*LDB + pos] = vv.y;
        Bs[(q*4+2)*LDB + pos] = vv.z;
        Bs[(q*4+3)*LDB + pos] = vv.w;
    }
    __syncthreads();

    float acc[8][8];
    float4 A0[8], A1[8];

    #pragma unroll 1
    for (int mc = 0; mc < 2; ++mc) {
        const int m0 = blockIdx.y * 256 + mc * 128;

        #pragma unroll
        for (int i = 0; i < 8; ++i)
            #pragma unroll
            for (int j = 0; j < 8; ++j) acc[i][j] = 0.f;

        #pragma unroll
        for (int i = 0; i < 8; ++i)
            A0[i] = *(const float4*)&y1[(size_t)(m0 + ty + i*16)*D + 0];

        int k = 0;
        #pragma unroll 1
        for (int it = 0; it < 12; ++it, k += 8) {
            #pragma unroll
            for (int i = 0; i < 8; ++i)
                A1[i] = *(const float4*)&y1[(size_t)(m0 + ty + i*16)*D + k + 4];
            GB_COMPUTE(A0, k);
            #pragma unroll
            for (int i = 0; i < 8; ++i)
                A0[i] = *(const float4*)&y1[(size_t)(m0 + ty + i*16)*D + k + 8];
            GB_COMPUTE(A1, k + 4);
        }
        GB_COMPUTE(A0, 96);   // k = 96..99 tail

        // store: each instr = 16 consecutive lanes -> 64 B contiguous/row
        #pragma unroll
        for (int i = 0; i < 8; ++i) {
            size_t row = (size_t)(m0 + ty + i*16) * NOUT;
            #pragma unroll
            for (int h = 0; h < 2; ++h)
                #pragma unroll
                for (int q = 0; q < 4; ++q) {
                    int n = n0 + h*64 + q*16 + tx;
                    if (n < NOUT) out[row + n] = acc[i][h*4+q];
                }
        }
    }
}

// ---------------------------------------------------------------------------
extern "C" void kernel_launch(void* const* d_in, const int* in_sizes, int n_in,
                              void* d_out, int out_size, void* d_ws, size_t ws_size,
                              hipStream_t stream)
{
    const float* adj_in  = (const float*)d_in[0];
    const float* adj_out = (const float*)d_in[1];
    const float* mask    = (const float*)d_in[2];
    const int*   item    = (const int*)  d_in[3];
    const int*   alias_  = (const int*)  d_in[4];
    const float* emb     = (const float*)d_in[6];
    const float* W_in    = (const float*)d_in[7];
    const float* b_in    = (const float*)d_in[8];
    const float* W_out   = (const float*)d_in[9];
    const float* b_out   = (const float*)d_in[10];
    const float* gate_k  = (const float*)d_in[11];
    const float* gate_b  = (const float*)d_in[12];
    const float* cand_k  = (const float*)d_in[13];
    const float* cand_b  = (const float*)d_in[14];
    const float* w1      = (const float*)d_in[15];
    const float* w2      = (const float*)d_in[16];
    const float* v       = (const float*)d_in[17];
    const float* nb      = (const float*)d_in[18];
    const float* Bm      = (const float*)d_in[19];
    float* out = (float*)d_out;
    float* y1  = (float*)d_ws;   // [512,100]

    ggnn_fused<<<BB, 512, 0, stream>>>(
        adj_in, adj_out, mask, item, alias_, emb,
        W_in, b_in, W_out, b_out, gate_k, gate_b, cand_k, cand_b,
        w1, w2, v, nb, Bm, y1);

    gemm_big<<<dim3((NOUT + 127)/128, 2), 256, 0, stream>>>(y1, emb, out);
}

// Round 9
// 626.596 us; speedup vs baseline: 1.1777x; 1.0048x over previous
//
#include <hip/hip_runtime.h>
#include <math.h>

#define D 100
#define T 50
#define BB 512
#define NOUT 99999

__device__ __forceinline__ float sigf(float x) { return 1.f / (1.f + expf(-x)); }

// ===========================================================================
// Fused per-batch GGNN + attention kernel. One 512-THREAD block per batch.
// 512 blocks / 256 CU = 2 blocks/CU -> 16 waves/CU (2x the 256-thread TLP).
// r8 lesson: t-groups of 5 doubled weight-load requests and ate the entire
// occupancy gain (VALUBusy pinned at 50%). P4 (dominant weight stream, 6
// quads/k-pair) therefore uses lane-pair K-split with t-groups of 10:
// pair owns (nq, 10 rows), lanes split K 50/50 -> round-4 weight reuse AT
// round-8 occupancy. shfl_xor(1) gives both lanes the summed gates; each
// lane sigmoids+writes 5 rows. VGPR must stay <= 128 (measured cliff).
// ===========================================================================
__global__ __launch_bounds__(512, 4) void ggnn_fused(
    const float* __restrict__ adj_in, const float* __restrict__ adj_out,
    const float* __restrict__ mask,   const int* __restrict__ item,
    const int* __restrict__ alias_,   const float* __restrict__ emb,
    const float* __restrict__ W_in,   const float* __restrict__ b_in,
    const float* __restrict__ W_out,  const float* __restrict__ b_out,
    const float* __restrict__ gate_k, const float* __restrict__ gate_b,
    const float* __restrict__ cand_k, const float* __restrict__ cand_b,
    const float* __restrict__ w1,     const float* __restrict__ w2,
    const float* __restrict__ v,      const float* __restrict__ nb,
    const float* __restrict__ Bm,     float* __restrict__ y1)
{
    __shared__ float hS[T*D];      // 20 KB
    __shared__ float R1[T*D];      // 20 KB
    __shared__ float R2[T*D];      // 20 KB
    __shared__ float maskS[T+2], vS[D], nbS[D], lastWS[D], coefS[T+2], maS[2*D];
    __shared__ int aliasS[T+2];
    __shared__ int rmidx;

    const int b = blockIdx.x, tid = threadIdx.x;
    const size_t bT = (size_t)b * T;

    // ---- P0: small stages ----
    if (tid < T) {
        aliasS[tid] = alias_[bT + tid];
        maskS[tid]  = mask[bT + tid];
    }
    if (tid >= 64 && tid < 64 + D) {
        int k = tid - 64;
        vS[k] = v[k]; nbS[k] = nb[k];
    }
    // ---- P1: h = emb[item] ----
    for (int idx = tid; idx < T*25; idx += 512) {
        int t = idx / 25, q = idx - t*25;
        int node = item[bT + t];
        *(float4*)&hS[t*D + q*4] = *(const float4*)&emb[(size_t)node*D + q*4];
    }
    __syncthreads();
    if (tid == 0) {
        float s = 0.f;
        for (int t = 0; t < T; ++t) s += maskS[t];
        rmidx = aliasS[(int)s - 1];
    }

    const bool act500 = tid < 500;

    // ---- P2: X1 = h@W_in+b_in -> R1 ; X2 = h@W_out+b_out -> R2 ----
    // thread = (which = tid/250, jq = rem%25, t-group of 5)
    if (act500) {
        const int which = tid / 250, rem = tid % 250;
        const int jq = rem % 25, t0 = (rem / 25) * 5;
        const float* W  = which ? W_out : W_in;
        const float* bb = which ? b_out : b_in;
        float4 binit = *(const float4*)&bb[jq*4];
        float4 acc[5];
        #pragma unroll
        for (int tt = 0; tt < 5; ++tt) acc[tt] = binit;
        for (int k = 0; k < D; k += 2) {
            float4 wa = *(const float4*)&W[k*D + jq*4];
            float4 wb = *(const float4*)&W[(k+1)*D + jq*4];
            #pragma unroll
            for (int tt = 0; tt < 5; ++tt) {
                float2 a = *(const float2*)&hS[(t0+tt)*D + k];
                acc[tt].x += a.x*wa.x + a.y*wb.x;
                acc[tt].y += a.x*wa.y + a.y*wb.y;
                acc[tt].z += a.x*wa.z + a.y*wb.z;
                acc[tt].w += a.x*wa.w + a.y*wb.w;
            }
        }
        float* dst = which ? R2 : R1;
        #pragma unroll
        for (int tt = 0; tt < 5; ++tt)
            *(float4*)&dst[(t0+tt)*D + jq*4] = acc[tt];
    }
    __syncthreads();

    // ---- P3: a_in = adj_in@X1, a_out = adj_out@X2 (into regs) ----
    float4 eacc[5];
    if (act500) {
        const int which = tid / 250, rem = tid % 250;
        const int jq = rem % 25, t0 = (rem / 25) * 5;
        const float* adj = which ? adj_out : adj_in;
        const float* Xs  = which ? R2 : R1;
        #pragma unroll
        for (int tt = 0; tt < 5; ++tt) eacc[tt] = make_float4(0.f,0.f,0.f,0.f);
        #pragma unroll 2
        for (int s = 0; s < T; ++s) {
            float4 x = *(const float4*)&Xs[s*D + jq*4];
            const float* ap = &adj[(bT + t0)*T + s];
            #pragma unroll
            for (int tt = 0; tt < 5; ++tt) {
                float a = ap[tt*T];
                eacc[tt].x += a*x.x; eacc[tt].y += a*x.y;
                eacc[tt].z += a*x.z; eacc[tt].w += a*x.w;
            }
        }
    }
    __syncthreads();                 // all X reads done
    // ---- P3b: write a_in -> R1, a_out -> R2 ----
    if (act500) {
        const int which = tid / 250, rem = tid % 250;
        const int jq = rem % 25, t0 = (rem / 25) * 5;
        float* dst = which ? R2 : R1;
        #pragma unroll
        for (int tt = 0; tt < 5; ++tt)
            *(float4*)&dst[(t0+tt)*D + jq*4] = eacc[tt];
    }
    __syncthreads();

    // ---- P4: gates = sigmoid([a_in|a_out|h] @ gate_k + gate_b) ----
    // lane-pair K-split, t-group of 10: pair p=tid>>1 owns (nq, t0);
    // kh=tid&1 takes K-half [kh*50, kh*50+50). Weight quad reused 10 rows.
    float4 gacc[10];
    if (act500) {
        const int p = tid >> 1, kh = tid & 1;
        const int nq = p % 50;
        const int t0 = (p / 50) * 10;
        float4 ginit = make_float4(0.f,0.f,0.f,0.f);
        if (!kh) ginit = *(const float4*)&gate_b[nq*4];
        #pragma unroll
        for (int tt = 0; tt < 10; ++tt) gacc[tt] = ginit;
        const int kb = kh * 50;
        for (int k = kb; k < kb + 50; k += 2) {
            float4 g0a = *(const float4*)&gate_k[(size_t)k*200 + nq*4];
            float4 g0b = *(const float4*)&gate_k[(size_t)(k+1)*200 + nq*4];
            float4 g1a = *(const float4*)&gate_k[(size_t)(k+100)*200 + nq*4];
            float4 g1b = *(const float4*)&gate_k[(size_t)(k+101)*200 + nq*4];
            float4 g2a = *(const float4*)&gate_k[(size_t)(k+200)*200 + nq*4];
            float4 g2b = *(const float4*)&gate_k[(size_t)(k+201)*200 + nq*4];
            #pragma unroll
            for (int tt = 0; tt < 10; ++tt) {
                float2 a0 = *(const float2*)&R1[(t0+tt)*D + k];
                float2 a1 = *(const float2*)&R2[(t0+tt)*D + k];
                float2 a2 = *(const float2*)&hS[(t0+tt)*D + k];
                gacc[tt].x += a0.x*g0a.x + a0.y*g0b.x + a1.x*g1a.x + a1.y*g1b.x + a2.x*g2a.x + a2.y*g2b.x;
                gacc[tt].y += a0.x*g0a.y + a0.y*g0b.y + a1.x*g1a.y + a1.y*g1b.y + a2.x*g2a.y + a2.y*g2b.y;
                gacc[tt].z += a0.x*g0a.z + a0.y*g0b.z + a1.x*g1a.z + a1.y*g1b.z + a2.x*g2a.z + a2.y*g2b.z;
                gacc[tt].w += a0.x*g0a.w + a0.y*g0b.w + a1.x*g1a.w + a1.y*g1b.w + a2.x*g2a.w + a2.y*g2b.w;
            }
        }
        // pair-sum: both lanes end with the full K gate pre-activation
        #pragma unroll
        for (int tt = 0; tt < 10; ++tt) {
            gacc[tt].x += __shfl_xor(gacc[tt].x, 1);
            gacc[tt].y += __shfl_xor(gacc[tt].y, 1);
            gacc[tt].z += __shfl_xor(gacc[tt].z, 1);
            gacc[tt].w += __shfl_xor(gacc[tt].w, 1);
        }
        // each lane finishes its own 5 of the pair's 10 rows
        #pragma unroll
        for (int tt = 0; tt < 5; ++tt) {
            int g = kh*5 + tt;
            gacc[g].x = sigf(gacc[g].x); gacc[g].y = sigf(gacc[g].y);
            gacc[g].z = sigf(gacc[g].z); gacc[g].w = sigf(gacc[g].w);
        }
    }

    // ---- P5a: cand partial (segments a_in, a_out) via lane-pair K-split ----
    // pair = (tid>>1): jq = pair%25, t-group of 5; kh = tid&1 picks segment
    float4 cacc[5];
    if (act500) {
        const int jq = (tid >> 1) % 25;
        const int t0 = ((tid >> 1) / 25) * 5;
        const int kh = tid & 1;
        const float* Ck = cand_k + (size_t)(kh ? 100 : 0) * D;
        const float* As = kh ? R2 : R1;
        float4 bq = *(const float4*)&cand_b[jq*4];
        float4 cinit = kh ? make_float4(0.f,0.f,0.f,0.f) : bq;
        #pragma unroll
        for (int tt = 0; tt < 5; ++tt) cacc[tt] = cinit;
        for (int k = 0; k < 100; k += 2) {
            float4 ca = *(const float4*)&Ck[(size_t)k*D + jq*4];
            float4 cb = *(const float4*)&Ck[(size_t)(k+1)*D + jq*4];
            #pragma unroll
            for (int tt = 0; tt < 5; ++tt) {
                float2 a = *(const float2*)&As[(t0+tt)*D + k];
                cacc[tt].x += a.x*ca.x + a.y*cb.x;
                cacc[tt].y += a.x*ca.y + a.y*cb.y;
                cacc[tt].z += a.x*ca.z + a.y*cb.z;
                cacc[tt].w += a.x*ca.w + a.y*cb.w;
            }
        }
    }
    __syncthreads();                 // R1/R2 (a_in/a_out) reads done

    // ---- P5b: r-owners write r*h -> R1 ; u-owners write u -> R2 ----
    // pair p owns (nq, 10 rows); lane kh writes its 5 rows
    if (act500) {
        const int p = tid >> 1, kh = tid & 1;
        const int nq = p % 50;
        const int t0 = (p / 50) * 10 + kh * 5;
        if (nq < 25) {
            #pragma unroll
            for (int tt = 0; tt < 5; ++tt) {
                float4 hh = *(const float4*)&hS[(t0+tt)*D + nq*4];
                float4 g = gacc[kh*5 + tt];
                float4 o; o.x = g.x*hh.x; o.y = g.y*hh.y; o.z = g.z*hh.z; o.w = g.w*hh.w;
                *(float4*)&R1[(t0+tt)*D + nq*4] = o;
            }
        } else {
            #pragma unroll
            for (int tt = 0; tt < 5; ++tt)
                *(float4*)&R2[(t0+tt)*D + (nq-25)*4] = gacc[kh*5 + tt];
        }
    }
    __syncthreads();

    // ---- P5c: cand seg3 (r*h) K-split + pair-reduce + tanh + h' -> hS ----
    if (act500) {
        const int jq = (tid >> 1) % 25;
        const int t0 = ((tid >> 1) / 25) * 5;
        const int kh = tid & 1;
        const float* Ck3 = cand_k + (size_t)(200 + kh*50) * D;
        for (int k = 0; k < 50; k += 2) {
            float4 ca = *(const float4*)&Ck3[(size_t)k*D + jq*4];
            float4 cb = *(const float4*)&Ck3[(size_t)(k+1)*D + jq*4];
            #pragma unroll
            for (int tt = 0; tt < 5; ++tt) {
                float2 rh = *(const float2*)&R1[(t0+tt)*D + kh*50 + k];
                cacc[tt].x += rh.x*ca.x + rh.y*cb.x;
                cacc[tt].y += rh.x*ca.y + rh.y*cb.y;
                cacc[tt].z += rh.x*ca.z + rh.y*cb.z;
                cacc[tt].w += rh.x*ca.w + rh.y*cb.w;
            }
        }
        #pragma unroll
        for (int tt = 0; tt < 5; ++tt) {
            cacc[tt].x += __shfl_xor(cacc[tt].x, 1);
            cacc[tt].y += __shfl_xor(cacc[tt].y, 1);
            cacc[tt].z += __shfl_xor(cacc[tt].z, 1);
            cacc[tt].w += __shfl_xor(cacc[tt].w, 1);
        }
        if (!kh) {
            #pragma unroll
            for (int tt = 0; tt < 5; ++tt) {
                float4 c4;
                c4.x = tanhf(cacc[tt].x); c4.y = tanhf(cacc[tt].y);
                c4.z = tanhf(cacc[tt].z); c4.w = tanhf(cacc[tt].w);
                float4 u4 = *(const float4*)&R2[(t0+tt)*D + jq*4];
                float4 hh = *(const float4*)&hS[(t0+tt)*D + jq*4];
                float4 o;
                o.x = u4.x*hh.x + (1.f-u4.x)*c4.x;
                o.y = u4.y*hh.y + (1.f-u4.y)*c4.y;
                o.z = u4.z*hh.z + (1.f-u4.z)*c4.z;
                o.w = u4.w*hh.w + (1.f-u4.w)*c4.w;
                *(float4*)&hS[(t0+tt)*D + jq*4] = o;
            }
        }
    }
    __syncthreads();

    // ---- P8: seqW[t] = h'[alias[t]] @ w2 -> R1 (K-split pairs);
    //          lastW = h'[rmidx] @ w1 on threads 500..511 ----
    if (act500) {
        const int jq = (tid >> 1) % 25;
        const int t0 = ((tid >> 1) / 25) * 5;
        const int kh = tid & 1;
        float4 sacc[5];
        #pragma unroll
        for (int tt = 0; tt < 5; ++tt) sacc[tt] = make_float4(0.f,0.f,0.f,0.f);
        int at[5];
        #pragma unroll
        for (int tt = 0; tt < 5; ++tt) at[tt] = aliasS[t0+tt];
        const float* Wp = w2 + (size_t)(kh*50) * D;
        for (int k = 0; k < 50; k += 2) {
            float4 wa = *(const float4*)&Wp[(size_t)k*D + jq*4];
            float4 wb = *(const float4*)&Wp[(size_t)(k+1)*D + jq*4];
            #pragma unroll
            for (int tt = 0; tt < 5; ++tt) {
                float2 a = *(const float2*)&hS[at[tt]*D + kh*50 + k];
                sacc[tt].x += a.x*wa.x + a.y*wb.x;
                sacc[tt].y += a.x*wa.y + a.y*wb.y;
                sacc[tt].z += a.x*wa.z + a.y*wb.z;
                sacc[tt].w += a.x*wa.w + a.y*wb.w;
            }
        }
        #pragma unroll
        for (int tt = 0; tt < 5; ++tt) {
            sacc[tt].x += __shfl_xor(sacc[tt].x, 1);
            sacc[tt].y += __shfl_xor(sacc[tt].y, 1);
            sacc[tt].z += __shfl_xor(sacc[tt].z, 1);
            sacc[tt].w += __shfl_xor(sacc[tt].w, 1);
        }
        if (!kh) {
            #pragma unroll
            for (int tt = 0; tt < 5; ++tt)
                *(float4*)&R1[(t0+tt)*D + jq*4] = sacc[tt];
        }
    } else {
        const int u = tid - 500;
        const int lid = rmidx;
        for (int jq = u; jq < 25; jq += 12) {
            float4 acc = make_float4(0.f,0.f,0.f,0.f);
            for (int k = 0; k < D; k += 2) {
                float4 wa = *(const float4*)&w1[(size_t)k*D + jq*4];
                float4 wb = *(const float4*)&w1[(size_t)(k+1)*D + jq*4];
                float2 a = *(const float2*)&hS[lid*D + k];
                acc.x += a.x*wa.x + a.y*wb.x;
                acc.y += a.x*wa.y + a.y*wb.y;
                acc.z += a.x*wa.z + a.y*wb.z;
                acc.w += a.x*wa.w + a.y*wb.w;
            }
            *(float4*)&lastWS[jq*4] = acc;
        }
    }
    __syncthreads();

    // ---- P9: coef[t] = mask[t] * sum_k v[k]*sigmoid(lastW[k]+seqW[t][k]+nb[k])
    if (tid < T) {
        float s = 0.f;
        #pragma unroll 4
        for (int k = 0; k < D; ++k) {
            float x = lastWS[k] + R1[tid*D + k] + nbS[k];
            s += vS[k] * sigf(x);
        }
        coefS[tid] = s * maskS[tid];
    }
    __syncthreads();
    // ---- P10: ma = [sum_t coef[t]*h'[alias[t]], lastW] ----
    if (tid < 25) {
        float4 acc = make_float4(0.f,0.f,0.f,0.f);
        #pragma unroll 5
        for (int t = 0; t < T; ++t) {
            float c = coefS[t];
            float4 hh = *(const float4*)&hS[aliasS[t]*D + tid*4];
            acc.x += c*hh.x; acc.y += c*hh.y; acc.z += c*hh.z; acc.w += c*hh.w;
        }
        *(float4*)&maS[tid*4] = acc;
    } else if (tid >= 32 && tid < 57) {
        int j4 = tid - 32;
        *(float4*)&maS[D + j4*4] = *(const float4*)&lastWS[j4*4];
    }
    __syncthreads();
    // ---- P11: y1[b] = ma @ B_mat ----
    if (tid < 25) {
        float4 acc = make_float4(0.f,0.f,0.f,0.f);
        #pragma unroll 4
        for (int k = 0; k < 2*D; ++k) {
            float a = maS[k];
            float4 w = *(const float4*)&Bm[(size_t)k*D + tid*4];
            acc.x += a*w.x; acc.y += a*w.y; acc.z += a*w.z; acc.w += a*w.w;
        }
        *(float4*)&y1[(size_t)b*D + tid*4] = acc;
    }
}

// ===========================================================================
// logits[512, 99999] = y1[512,100] @ emb[1:,:]^T
// B-stationary: one block per 128-col n-tile x 256-row m-half; B tile staged
// once (52.8 KB LDS), 2 m-chunks of 128 rows; A (y1) from L2 broadcast loads.
// Bs columns stored PERMUTED: col (h*64 + j*16 + tx) at slot (h*64 + tx*4 + j)
// so each thread's 8 owned columns are two ds_read_b128 (was 8 scalar reads
// per kk -> 4x fewer LDS issue cycles), while stores keep the 64 B-contiguous
// {tx,+16,+32,+48} instruction pattern (float4 stores impossible: NOUT=99999
// makes 3/4 of out rows 16B-misaligned).
// ===========================================================================
#define LDB 132   // divisible by 4 -> b128-aligned rows; 52.8 KB total

#define GB_COMPUTE(Ab, kbase) do {                                            \
    _Pragma("unroll")                                                         \
    for (int kk = 0; kk < 4; ++kk) {                                          \
        float4 b0 = *(const float4*)&Bs[(kbase + kk)*LDB + tx*4];             \
        float4 b1 = *(const float4*)&Bs[(kbase + kk)*LDB + 64 + tx*4];        \
        _Pragma("unroll")                                                     \
        for (int i = 0; i < 8; ++i) {                                         \
            float a_ = kk==0 ? Ab[i].x : kk==1 ? Ab[i].y :                    \
                       kk==2 ? Ab[i].z : Ab[i].w;                             \
            acc[i][0] += a_*b0.x; acc[i][1] += a_*b0.y;                       \
            acc[i][2] += a_*b0.z; acc[i][3] += a_*b0.w;                       \
            acc[i][4] += a_*b1.x; acc[i][5] += a_*b1.y;                       \
            acc[i][6] += a_*b1.z; acc[i][7] += a_*b1.w;                       \
        }                                                                     \
    }                                                                         \
} while (0)

__global__ __launch_bounds__(256) void gemm_big(
    const float* __restrict__ y1,
    const float* __restrict__ emb,
    float* __restrict__ out)
{
    __shared__ float Bs[100*LDB];          // 52.8 KB
    const int tid = threadIdx.x;
    const int tx = tid & 15, ty = tid >> 4;
    const int n0 = blockIdx.x * 128;

    // stage B: cols n0..n0+127, k=0..99, transposed + column-permuted
    for (int idx = tid; idx < 128*25; idx += 256) {
        int n = idx / 25, q = idx - n*25;
        int gn = n0 + n;
        float4 vv = make_float4(0.f,0.f,0.f,0.f);
        if (gn < NOUT) vv = *(const float4*)&emb[(size_t)(gn+1)*D + q*4];
        int w = n & 63;
        int pos = (n & 64) + ((w & 15) << 2) + (w >> 4);
        Bs[(q*4+0)*LDB + pos] = vv.x;
        Bs[(q*4+1)*LDB + pos] = vv.y;
        Bs[(q*4+2)*LDB + pos] = vv.z;
        Bs[(q*4+3)*LDB + pos] = vv.w;
    }
    __syncthreads();

    float acc[8][8];
    float4 A0[8], A1[8];

    #pragma unroll 1
    for (int mc = 0; mc < 2; ++mc) {
        const int m0 = blockIdx.y * 256 + mc * 128;

        #pragma unroll
        for (int i = 0; i < 8; ++i)
            #pragma unroll
            for (int j = 0; j < 8; ++j) acc[i][j] = 0.f;

        #pragma unroll
        for (int i = 0; i < 8; ++i)
            A0[i] = *(const float4*)&y1[(size_t)(m0 + ty + i*16)*D + 0];

        int k = 0;
        #pragma unroll 1
        for (int it = 0; it < 12; ++it, k += 8) {
            #pragma unroll
            for (int i = 0; i < 8; ++i)
                A1[i] = *(const float4*)&y1[(size_t)(m0 + ty + i*16)*D + k + 4];
            GB_COMPUTE(A0, k);
            #pragma unroll
            for (int i = 0; i < 8; ++i)
                A0[i] = *(const float4*)&y1[(size_t)(m0 + ty + i*16)*D + k + 8];
            GB_COMPUTE(A1, k + 4);
        }
        GB_COMPUTE(A0, 96);   // k = 96..99 tail

        // store: each instr = 16 consecutive lanes -> 64 B contiguous/row
        #pragma unroll
        for (int i = 0; i < 8; ++i) {
            size_t row = (size_t)(m0 + ty + i*16) * NOUT;
            #pragma unroll
            for (int h = 0; h < 2; ++h)
                #pragma unroll
                for (int q = 0; q < 4; ++q) {
                    int n = n0 + h*64 + q*16 + tx;
                    if (n < NOUT) out[row + n] = acc[i][h*4+q];
                }
        }
    }
}

// ---------------------------------------------------------------------------
extern "C" void kernel_launch(void* const* d_in, const int* in_sizes, int n_in,
                              void* d_out, int out_size, void* d_ws, size_t ws_size,
                              hipStream_t stream)
{
    const float* adj_in  = (const float*)d_in[0];
    const float* adj_out = (const float*)d_in[1];
    const float* mask    = (const float*)d_in[2];
    const int*   item    = (const int*)  d_in[3];
    const int*   alias_  = (const int*)  d_in[4];
    const float* emb     = (const float*)d_in[6];
    const float* W_in    = (const float*)d_in[7];
    const float* b_in    = (const float*)d_in[8];
    const float* W_out   = (const float*)d_in[9];
    const float* b_out   = (const float*)d_in[10];
    const float* gate_k  = (const float*)d_in[11];
    const float* gate_b  = (const float*)d_in[12];
    const float* cand_k  = (const float*)d_in[13];
    const float* cand_b  = (const float*)d_in[14];
    const float* w1      = (const float*)d_in[15];
    const float* w2      = (const float*)d_in[16];
    const float* v       = (const float*)d_in[17];
    const float* nb      = (const float*)d_in[18];
    const float* Bm      = (const float*)d_in[19];
    float* out = (float*)d_out;
    float* y1  = (float*)d_ws;   // [512,100]

    ggnn_fused<<<BB, 512, 0, stream>>>(
        adj_in, adj_out, mask, item, alias_, emb,
        W_in, b_in, W_out, b_out, gate_k, gate_b, cand_k, cand_b,
        w1, w2, v, nb, Bm, y1);

    gemm_big<<<dim3((NOUT + 127)/128, 2), 256, 0, stream>>>(y1, emb, out);
}

// Round 10
// 620.756 us; speedup vs baseline: 1.1887x; 1.0094x over previous
//
#include <hip/hip_runtime.h>
#include <math.h>

#define D 100
#define T 50
#define BB 512
#define NOUT 99999

__device__ __forceinline__ float sigf(float x) { return 1.f / (1.f + expf(-x)); }

// ===========================================================================
// Fused per-batch GGNN + attention kernel. One 512-THREAD block per batch.
// 512 blocks / 256 CU = 2 blocks/CU -> 16 waves/CU. P4 uses lane-pair
// K-split with t-groups of 10 (round-4 weight reuse AT round-8 occupancy).
// r9 lesson (rule #20): gacc[kh*5+tt] with runtime kh sent the whole array
// to SCRATCH (96 MB spill writes, VALUBusy 39%). All register indices are
// now compile-time via explicit kh branches; LDS addresses stay runtime.
// VGPR must stay <= 128 (measured cliff at 512 threads: 16 waves/CU).
// ===========================================================================
__global__ __launch_bounds__(512, 4) void ggnn_fused(
    const float* __restrict__ adj_in, const float* __restrict__ adj_out,
    const float* __restrict__ mask,   const int* __restrict__ item,
    const int* __restrict__ alias_,   const float* __restrict__ emb,
    const float* __restrict__ W_in,   const float* __restrict__ b_in,
    const float* __restrict__ W_out,  const float* __restrict__ b_out,
    const float* __restrict__ gate_k, const float* __restrict__ gate_b,
    const float* __restrict__ cand_k, const float* __restrict__ cand_b,
    const float* __restrict__ w1,     const float* __restrict__ w2,
    const float* __restrict__ v,      const float* __restrict__ nb,
    const float* __restrict__ Bm,     float* __restrict__ y1)
{
    __shared__ float hS[T*D];      // 20 KB
    __shared__ float R1[T*D];      // 20 KB
    __shared__ float R2[T*D];      // 20 KB
    __shared__ float maskS[T+2], vS[D], nbS[D], lastWS[D], coefS[T+2], maS[2*D];
    __shared__ int aliasS[T+2];
    __shared__ int rmidx;

    const int b = blockIdx.x, tid = threadIdx.x;
    const size_t bT = (size_t)b * T;

    // ---- P0: small stages ----
    if (tid < T) {
        aliasS[tid] = alias_[bT + tid];
        maskS[tid]  = mask[bT + tid];
    }
    if (tid >= 64 && tid < 64 + D) {
        int k = tid - 64;
        vS[k] = v[k]; nbS[k] = nb[k];
    }
    // ---- P1: h = emb[item] ----
    for (int idx = tid; idx < T*25; idx += 512) {
        int t = idx / 25, q = idx - t*25;
        int node = item[bT + t];
        *(float4*)&hS[t*D + q*4] = *(const float4*)&emb[(size_t)node*D + q*4];
    }
    __syncthreads();
    if (tid == 0) {
        float s = 0.f;
        for (int t = 0; t < T; ++t) s += maskS[t];
        rmidx = aliasS[(int)s - 1];
    }

    const bool act500 = tid < 500;

    // ---- P2: X1 = h@W_in+b_in -> R1 ; X2 = h@W_out+b_out -> R2 ----
    // thread = (which = tid/250, jq = rem%25, t-group of 5)
    if (act500) {
        const int which = tid / 250, rem = tid % 250;
        const int jq = rem % 25, t0 = (rem / 25) * 5;
        const float* W  = which ? W_out : W_in;
        const float* bb = which ? b_out : b_in;
        float4 binit = *(const float4*)&bb[jq*4];
        float4 acc[5];
        #pragma unroll
        for (int tt = 0; tt < 5; ++tt) acc[tt] = binit;
        for (int k = 0; k < D; k += 2) {
            float4 wa = *(const float4*)&W[k*D + jq*4];
            float4 wb = *(const float4*)&W[(k+1)*D + jq*4];
            #pragma unroll
            for (int tt = 0; tt < 5; ++tt) {
                float2 a = *(const float2*)&hS[(t0+tt)*D + k];
                acc[tt].x += a.x*wa.x + a.y*wb.x;
                acc[tt].y += a.x*wa.y + a.y*wb.y;
                acc[tt].z += a.x*wa.z + a.y*wb.z;
                acc[tt].w += a.x*wa.w + a.y*wb.w;
            }
        }
        float* dst = which ? R2 : R1;
        #pragma unroll
        for (int tt = 0; tt < 5; ++tt)
            *(float4*)&dst[(t0+tt)*D + jq*4] = acc[tt];
    }
    __syncthreads();

    // ---- P3: a_in = adj_in@X1, a_out = adj_out@X2 (into regs) ----
    float4 eacc[5];
    if (act500) {
        const int which = tid / 250, rem = tid % 250;
        const int jq = rem % 25, t0 = (rem / 25) * 5;
        const float* adj = which ? adj_out : adj_in;
        const float* Xs  = which ? R2 : R1;
        #pragma unroll
        for (int tt = 0; tt < 5; ++tt) eacc[tt] = make_float4(0.f,0.f,0.f,0.f);
        #pragma unroll 2
        for (int s = 0; s < T; ++s) {
            float4 x = *(const float4*)&Xs[s*D + jq*4];
            const float* ap = &adj[(bT + t0)*T + s];
            #pragma unroll
            for (int tt = 0; tt < 5; ++tt) {
                float a = ap[tt*T];
                eacc[tt].x += a*x.x; eacc[tt].y += a*x.y;
                eacc[tt].z += a*x.z; eacc[tt].w += a*x.w;
            }
        }
    }
    __syncthreads();                 // all X reads done
    // ---- P3b: write a_in -> R1, a_out -> R2 ----
    if (act500) {
        const int which = tid / 250, rem = tid % 250;
        const int jq = rem % 25, t0 = (rem / 25) * 5;
        float* dst = which ? R2 : R1;
        #pragma unroll
        for (int tt = 0; tt < 5; ++tt)
            *(float4*)&dst[(t0+tt)*D + jq*4] = eacc[tt];
    }
    __syncthreads();

    // ---- P4: gates = sigmoid([a_in|a_out|h] @ gate_k + gate_b) ----
    // lane-pair K-split, t-group of 10: pair p=tid>>1 owns (nq, t0);
    // kh=tid&1 takes K-half [kh*50, kh*50+50). Weight quad reused 10 rows.
    // ALL gacc indices compile-time (kh branches) to avoid scratch (r9 bug).
    float4 gacc[10];
    if (act500) {
        const int p = tid >> 1, kh = tid & 1;
        const int nq = p % 50;
        const int t0 = (p / 50) * 10;
        float4 ginit = make_float4(0.f,0.f,0.f,0.f);
        if (!kh) ginit = *(const float4*)&gate_b[nq*4];
        #pragma unroll
        for (int tt = 0; tt < 10; ++tt) gacc[tt] = ginit;
        const int kb = kh * 50;
        for (int k = kb; k < kb + 50; k += 2) {
            float4 g0a = *(const float4*)&gate_k[(size_t)k*200 + nq*4];
            float4 g0b = *(const float4*)&gate_k[(size_t)(k+1)*200 + nq*4];
            float4 g1a = *(const float4*)&gate_k[(size_t)(k+100)*200 + nq*4];
            float4 g1b = *(const float4*)&gate_k[(size_t)(k+101)*200 + nq*4];
            float4 g2a = *(const float4*)&gate_k[(size_t)(k+200)*200 + nq*4];
            float4 g2b = *(const float4*)&gate_k[(size_t)(k+201)*200 + nq*4];
            #pragma unroll
            for (int tt = 0; tt < 10; ++tt) {
                float2 a0 = *(const float2*)&R1[(t0+tt)*D + k];
                float2 a1 = *(const float2*)&R2[(t0+tt)*D + k];
                float2 a2 = *(const float2*)&hS[(t0+tt)*D + k];
                gacc[tt].x += a0.x*g0a.x + a0.y*g0b.x + a1.x*g1a.x + a1.y*g1b.x + a2.x*g2a.x + a2.y*g2b.x;
                gacc[tt].y += a0.x*g0a.y + a0.y*g0b.y + a1.x*g1a.y + a1.y*g1b.y + a2.x*g2a.y + a2.y*g2b.y;
                gacc[tt].z += a0.x*g0a.z + a0.y*g0b.z + a1.x*g1a.z + a1.y*g1b.z + a2.x*g2a.z + a2.y*g2b.z;
                gacc[tt].w += a0.x*g0a.w + a0.y*g0b.w + a1.x*g1a.w + a1.y*g1b.w + a2.x*g2a.w + a2.y*g2b.w;
            }
        }
        // pair-sum: both lanes end with the full K gate pre-activation
        #pragma unroll
        for (int tt = 0; tt < 10; ++tt) {
            gacc[tt].x += __shfl_xor(gacc[tt].x, 1);
            gacc[tt].y += __shfl_xor(gacc[tt].y, 1);
            gacc[tt].z += __shfl_xor(gacc[tt].z, 1);
            gacc[tt].w += __shfl_xor(gacc[tt].w, 1);
        }
        // each lane finishes its own 5 of the pair's 10 rows (const indices)
        if (!kh) {
            #pragma unroll
            for (int tt = 0; tt < 5; ++tt) {
                gacc[tt].x = sigf(gacc[tt].x); gacc[tt].y = sigf(gacc[tt].y);
                gacc[tt].z = sigf(gacc[tt].z); gacc[tt].w = sigf(gacc[tt].w);
            }
        } else {
            #pragma unroll
            for (int tt = 0; tt < 5; ++tt) {
                gacc[5+tt].x = sigf(gacc[5+tt].x); gacc[5+tt].y = sigf(gacc[5+tt].y);
                gacc[5+tt].z = sigf(gacc[5+tt].z); gacc[5+tt].w = sigf(gacc[5+tt].w);
            }
        }
    }

    // ---- P5a: cand partial (segments a_in, a_out) via lane-pair K-split ----
    // pair = (tid>>1): jq = pair%25, t-group of 5; kh = tid&1 picks segment
    float4 cacc[5];
    if (act500) {
        const int jq = (tid >> 1) % 25;
        const int t0 = ((tid >> 1) / 25) * 5;
        const int kh = tid & 1;
        const float* Ck = cand_k + (size_t)(kh ? 100 : 0) * D;
        const float* As = kh ? R2 : R1;
        float4 bq = *(const float4*)&cand_b[jq*4];
        float4 cinit = kh ? make_float4(0.f,0.f,0.f,0.f) : bq;
        #pragma unroll
        for (int tt = 0; tt < 5; ++tt) cacc[tt] = cinit;
        for (int k = 0; k < 100; k += 2) {
            float4 ca = *(const float4*)&Ck[(size_t)k*D + jq*4];
            float4 cb = *(const float4*)&Ck[(size_t)(k+1)*D + jq*4];
            #pragma unroll
            for (int tt = 0; tt < 5; ++tt) {
                float2 a = *(const float2*)&As[(t0+tt)*D + k];
                cacc[tt].x += a.x*ca.x + a.y*cb.x;
                cacc[tt].y += a.x*ca.y + a.y*cb.y;
                cacc[tt].z += a.x*ca.z + a.y*cb.z;
                cacc[tt].w += a.x*ca.w + a.y*cb.w;
            }
        }
    }
    __syncthreads();                 // R1/R2 (a_in/a_out) reads done

    // ---- P5b: r-owners write r*h -> R1 ; u-owners write u -> R2 ----
    // pair p owns (nq, 10 rows); lane kh writes its 5 rows (const reg idx)
    if (act500) {
        const int p = tid >> 1, kh = tid & 1;
        const int nq = p % 50;
        const int t0 = (p / 50) * 10 + kh * 5;   // runtime addr base: OK
        if (nq < 25) {
            if (!kh) {
                #pragma unroll
                for (int tt = 0; tt < 5; ++tt) {
                    float4 hh = *(const float4*)&hS[(t0+tt)*D + nq*4];
                    float4 g = gacc[tt];
                    float4 o; o.x = g.x*hh.x; o.y = g.y*hh.y; o.z = g.z*hh.z; o.w = g.w*hh.w;
                    *(float4*)&R1[(t0+tt)*D + nq*4] = o;
                }
            } else {
                #pragma unroll
                for (int tt = 0; tt < 5; ++tt) {
                    float4 hh = *(const float4*)&hS[(t0+tt)*D + nq*4];
                    float4 g = gacc[5+tt];
                    float4 o; o.x = g.x*hh.x; o.y = g.y*hh.y; o.z = g.z*hh.z; o.w = g.w*hh.w;
                    *(float4*)&R1[(t0+tt)*D + nq*4] = o;
                }
            }
        } else {
            if (!kh) {
                #pragma unroll
                for (int tt = 0; tt < 5; ++tt)
                    *(float4*)&R2[(t0+tt)*D + (nq-25)*4] = gacc[tt];
            } else {
                #pragma unroll
                for (int tt = 0; tt < 5; ++tt)
                    *(float4*)&R2[(t0+tt)*D + (nq-25)*4] = gacc[5+tt];
            }
        }
    }
    __syncthreads();

    // ---- P5c: cand seg3 (r*h) K-split + pair-reduce + tanh + h' -> hS ----
    if (act500) {
        const int jq = (tid >> 1) % 25;
        const int t0 = ((tid >> 1) / 25) * 5;
        const int kh = tid & 1;
        const float* Ck3 = cand_k + (size_t)(200 + kh*50) * D;
        for (int k = 0; k < 50; k += 2) {
            float4 ca = *(const float4*)&Ck3[(size_t)k*D + jq*4];
            float4 cb = *(const float4*)&Ck3[(size_t)(k+1)*D + jq*4];
            #pragma unroll
            for (int tt = 0; tt < 5; ++tt) {
                float2 rh = *(const float2*)&R1[(t0+tt)*D + kh*50 + k];
                cacc[tt].x += rh.x*ca.x + rh.y*cb.x;
                cacc[tt].y += rh.x*ca.y + rh.y*cb.y;
                cacc[tt].z += rh.x*ca.z + rh.y*cb.z;
                cacc[tt].w += rh.x*ca.w + rh.y*cb.w;
            }
        }
        #pragma unroll
        for (int tt = 0; tt < 5; ++tt) {
            cacc[tt].x += __shfl_xor(cacc[tt].x, 1);
            cacc[tt].y += __shfl_xor(cacc[tt].y, 1);
            cacc[tt].z += __shfl_xor(cacc[tt].z, 1);
            cacc[tt].w += __shfl_xor(cacc[tt].w, 1);
        }
        if (!kh) {
            #pragma unroll
            for (int tt = 0; tt < 5; ++tt) {
                float4 c4;
                c4.x = tanhf(cacc[tt].x); c4.y = tanhf(cacc[tt].y);
                c4.z = tanhf(cacc[tt].z); c4.w = tanhf(cacc[tt].w);
                float4 u4 = *(const float4*)&R2[(t0+tt)*D + jq*4];
                float4 hh = *(const float4*)&hS[(t0+tt)*D + jq*4];
                float4 o;
                o.x = u4.x*hh.x + (1.f-u4.x)*c4.x;
                o.y = u4.y*hh.y + (1.f-u4.y)*c4.y;
                o.z = u4.z*hh.z + (1.f-u4.z)*c4.z;
                o.w = u4.w*hh.w + (1.f-u4.w)*c4.w;
                *(float4*)&hS[(t0+tt)*D + jq*4] = o;
            }
        }
    }
    __syncthreads();

    // ---- P8: seqW[t] = h'[alias[t]] @ w2 -> R1 (K-split pairs);
    //          lastW = h'[rmidx] @ w1 on threads 500..511 ----
    if (act500) {
        const int jq = (tid >> 1) % 25;
        const int t0 = ((tid >> 1) / 25) * 5;
        const int kh = tid & 1;
        float4 sacc[5];
        #pragma unroll
        for (int tt = 0; tt < 5; ++tt) sacc[tt] = make_float4(0.f,0.f,0.f,0.f);
        int at[5];
        #pragma unroll
        for (int tt = 0; tt < 5; ++tt) at[tt] = aliasS[t0+tt];
        const float* Wp = w2 + (size_t)(kh*50) * D;
        for (int k = 0; k < 50; k += 2) {
            float4 wa = *(const float4*)&Wp[(size_t)k*D + jq*4];
            float4 wb = *(const float4*)&Wp[(size_t)(k+1)*D + jq*4];
            #pragma unroll
            for (int tt = 0; tt < 5; ++tt) {
                float2 a = *(const float2*)&hS[at[tt]*D + kh*50 + k];
                sacc[tt].x += a.x*wa.x + a.y*wb.x;
                sacc[tt].y += a.x*wa.y + a.y*wb.y;
                sacc[tt].z += a.x*wa.z + a.y*wb.z;
                sacc[tt].w += a.x*wa.w + a.y*wb.w;
            }
        }
        #pragma unroll
        for (int tt = 0; tt < 5; ++tt) {
            sacc[tt].x += __shfl_xor(sacc[tt].x, 1);
            sacc[tt].y += __shfl_xor(sacc[tt].y, 1);
            sacc[tt].z += __shfl_xor(sacc[tt].z, 1);
            sacc[tt].w += __shfl_xor(sacc[tt].w, 1);
        }
        if (!kh) {
            #pragma unroll
            for (int tt = 0; tt < 5; ++tt)
                *(float4*)&R1[(t0+tt)*D + jq*4] = sacc[tt];
        }
    } else {
        const int u = tid - 500;
        const int lid = rmidx;
        for (int jq = u; jq < 25; jq += 12) {
            float4 acc = make_float4(0.f,0.f,0.f,0.f);
            for (int k = 0; k < D; k += 2) {
                float4 wa = *(const float4*)&w1[(size_t)k*D + jq*4];
                float4 wb = *(const float4*)&w1[(size_t)(k+1)*D + jq*4];
                float2 a = *(const float2*)&hS[lid*D + k];
                acc.x += a.x*wa.x + a.y*wb.x;
                acc.y += a.x*wa.y + a.y*wb.y;
                acc.z += a.x*wa.z + a.y*wb.z;
                acc.w += a.x*wa.w + a.y*wb.w;
            }
            *(float4*)&lastWS[jq*4] = acc;
        }
    }
    __syncthreads();

    // ---- P9: coef[t] = mask[t] * sum_k v[k]*sigmoid(lastW[k]+seqW[t][k]+nb[k])
    if (tid < T) {
        float s = 0.f;
        #pragma unroll 4
        for (int k = 0; k < D; ++k) {
            float x = lastWS[k] + R1[tid*D + k] + nbS[k];
            s += vS[k] * sigf(x);
        }
        coefS[tid] = s * maskS[tid];
    }
    __syncthreads();
    // ---- P10: ma = [sum_t coef[t]*h'[alias[t]], lastW] ----
    if (tid < 25) {
        float4 acc = make_float4(0.f,0.f,0.f,0.f);
        #pragma unroll 5
        for (int t = 0; t < T; ++t) {
            float c = coefS[t];
            float4 hh = *(const float4*)&hS[aliasS[t]*D + tid*4];
            acc.x += c*hh.x; acc.y += c*hh.y; acc.z += c*hh.z; acc.w += c*hh.w;
        }
        *(float4*)&maS[tid*4] = acc;
    } else if (tid >= 32 && tid < 57) {
        int j4 = tid - 32;
        *(float4*)&maS[D + j4*4] = *(const float4*)&lastWS[j4*4];
    }
    __syncthreads();
    // ---- P11: y1[b] = ma @ B_mat ----
    if (tid < 25) {
        float4 acc = make_float4(0.f,0.f,0.f,0.f);
        #pragma unroll 4
        for (int k = 0; k < 2*D; ++k) {
            float a = maS[k];
            float4 w = *(const float4*)&Bm[(size_t)k*D + tid*4];
            acc.x += a*w.x; acc.y += a*w.y; acc.z += a*w.z; acc.w += a*w.w;
        }
        *(float4*)&y1[(size_t)b*D + tid*4] = acc;
    }
}

// ===========================================================================
// logits[512, 99999] = y1[512,100] @ emb[1:,:]^T
// B-stationary: one block per 128-col n-tile x 256-row m-half; B tile staged
// once (52.8 KB LDS), 2 m-chunks of 128 rows; A (y1) from L2 broadcast loads.
// Bs columns stored PERMUTED: col (h*64 + j*16 + tx) at slot (h*64 + tx*4 + j)
// so each thread's 8 owned columns are two ds_read_b128 (was 8 scalar reads
// per kk -> 4x fewer LDS issue cycles), while stores keep the 64 B-contiguous
// {tx,+16,+32,+48} instruction pattern (float4 stores impossible: NOUT=99999
// makes 3/4 of out rows 16B-misaligned).
// ===========================================================================
#define LDB 132   // divisible by 4 -> b128-aligned rows; 52.8 KB total

#define GB_COMPUTE(Ab, kbase) do {                                            \
    _Pragma("unroll")                                                         \
    for (int kk = 0; kk < 4; ++kk) {                                          \
        float4 b0 = *(const float4*)&Bs[(kbase + kk)*LDB + tx*4];             \
        float4 b1 = *(const float4*)&Bs[(kbase + kk)*LDB + 64 + tx*4];        \
        _Pragma("unroll")                                                     \
        for (int i = 0; i < 8; ++i) {                                         \
            float a_ = kk==0 ? Ab[i].x : kk==1 ? Ab[i].y :                    \
                       kk==2 ? Ab[i].z : Ab[i].w;                             \
            acc[i][0] += a_*b0.x; acc[i][1] += a_*b0.y;                       \
            acc[i][2] += a_*b0.z; acc[i][3] += a_*b0.w;                       \
            acc[i][4] += a_*b1.x; acc[i][5] += a_*b1.y;                       \
            acc[i][6] += a_*b1.z; acc[i][7] += a_*b1.w;                       \
        }                                                                     \
    }                                                                         \
} while (0)

__global__ __launch_bounds__(256) void gemm_big(
    const float* __restrict__ y1,
    const float* __restrict__ emb,
    float* __restrict__ out)
{
    __shared__ float Bs[100*LDB];          // 52.8 KB
    const int tid = threadIdx.x;
    const int tx = tid & 15, ty = tid >> 4;
    const int n0 = blockIdx.x * 128;

    // stage B: cols n0..n0+127, k=0..99, transposed + column-permuted
    for (int idx = tid; idx < 128*25; idx += 256) {
        int n = idx / 25, q = idx - n*25;
        int gn = n0 + n;
        float4 vv = make_float4(0.f,0.f,0.f,0.f);
        if (gn < NOUT) vv = *(const float4*)&emb[(size_t)(gn+1)*D + q*4];
        int w = n & 63;
        int pos = (n & 64) + ((w & 15) << 2) + (w >> 4);
        Bs[(q*4+0)*LDB + pos] = vv.x;
        Bs[(q*4+1)*LDB + pos] = vv.y;
        Bs[(q*4+2)*LDB + pos] = vv.z;
        Bs[(q*4+3)*LDB + pos] = vv.w;
    }
    __syncthreads();

    float acc[8][8];
    float4 A0[8], A1[8];

    #pragma unroll 1
    for (int mc = 0; mc < 2; ++mc) {
        const int m0 = blockIdx.y * 256 + mc * 128;

        #pragma unroll
        for (int i = 0; i < 8; ++i)
            #pragma unroll
            for (int j = 0; j < 8; ++j) acc[i][j] = 0.f;

        #pragma unroll
        for (int i = 0; i < 8; ++i)
            A0[i] = *(const float4*)&y1[(size_t)(m0 + ty + i*16)*D + 0];

        int k = 0;
        #pragma unroll 1
        for (int it = 0; it < 12; ++it, k += 8) {
            #pragma unroll
            for (int i = 0; i < 8; ++i)
                A1[i] = *(const float4*)&y1[(size_t)(m0 + ty + i*16)*D + k + 4];
            GB_COMPUTE(A0, k);
            #pragma unroll
            for (int i = 0; i < 8; ++i)
                A0[i] = *(const float4*)&y1[(size_t)(m0 + ty + i*16)*D + k + 8];
            GB_COMPUTE(A1, k + 4);
        }
        GB_COMPUTE(A0, 96);   // k = 96..99 tail

        // store: each instr = 16 consecutive lanes -> 64 B contiguous/row
        #pragma unroll
        for (int i = 0; i < 8; ++i) {
            size_t row = (size_t)(m0 + ty + i*16) * NOUT;
            #pragma unroll
            for (int h = 0; h < 2; ++h)
                #pragma unroll
                for (int q = 0; q < 4; ++q) {
                    int n = n0 + h*64 + q*16 + tx;
                    if (n < NOUT) out[row + n] = acc[i][h*4+q];
                }
        }
    }
}

// ---------------------------------------------------------------------------
extern "C" void kernel_launch(void* const* d_in, const int* in_sizes, int n_in,
                              void* d_out, int out_size, void* d_ws, size_t ws_size,
                              hipStream_t stream)
{
    const float* adj_in  = (const float*)d_in[0];
    const float* adj_out = (const float*)d_in[1];
    const float* mask    = (const float*)d_in[2];
    const int*   item    = (const int*)  d_in[3];
    const int*   alias_  = (const int*)  d_in[4];
    const float* emb     = (const float*)d_in[6];
    const float* W_in    = (const float*)d_in[7];
    const float* b_in    = (const float*)d_in[8];
    const float* W_out   = (const float*)d_in[9];
    const float* b_out   = (const float*)d_in[10];
    const float* gate_k  = (const float*)d_in[11];
    const float* gate_b  = (const float*)d_in[12];
    const float* cand_k  = (const float*)d_in[13];
    const float* cand_b  = (const float*)d_in[14];
    const float* w1      = (const float*)d_in[15];
    const float* w2      = (const float*)d_in[16];
    const float* v       = (const float*)d_in[17];
    const float* nb      = (const float*)d_in[18];
    const float* Bm      = (const float*)d_in[19];
    float* out = (float*)d_out;
    float* y1  = (float*)d_ws;   // [512,100]

    ggnn_fused<<<BB, 512, 0, stream>>>(
        adj_in, adj_out, mask, item, alias_, emb,
        W_in, b_in, W_out, b_out, gate_k, gate_b, cand_k, cand_b,
        w1, w2, v, nb, Bm, y1);

    gemm_big<<<dim3((NOUT + 127)/128, 2), 256, 0, stream>>>(y1, emb, out);
}